// Round 1
// baseline (5702.641 us; speedup 1.0000x reference)
//
#include <hip/hip_runtime.h>
#include <math.h>

// ---------------------------------------------------------------------------
// SRResNet_10: 23 conv3x3 layers, all fp32.
//   x[4,3,128,128] -> inconv -> 10x {modconv+relu, modconv+residual} at 64ch
//   -> 2x (conv 64->256 + pixelshuffle2) -> conv 64->3 -> out[4,3,512,512]
// Modulation folds into input-channel scaling; pixel shuffle folds into
// conv epilogue indexing. Static device buffers (no ws_size assumption).
// ---------------------------------------------------------------------------

__device__ float g_bufA[4 * 64 * 128 * 128];   // fea ping
__device__ float g_bufB[4 * 64 * 128 * 128];   // fea pong
__device__ float g_bufC[4 * 64 * 256 * 256];   // after up-stage 0 (shuffled)
__device__ float g_bufE[4 * 64 * 512 * 512];   // after up-stage 1 (shuffled)
__device__ float g_mod[20 * 4 * 64];           // modulation feats [m][b][ic]

// --- modulation: feats[m,b,o] = s_lin * sum_c cf[b,c]*mod_w[m,o,c] + mod_b[m,o]
__global__ void mod_kernel(const float* __restrict__ cf,
                           const float* __restrict__ mw,
                           const float* __restrict__ mb,
                           float* __restrict__ mod) {
    int m = blockIdx.x;      // 0..19
    int b = blockIdx.y;      // 0..3
    int o = threadIdx.x;     // 0..63
    const float* wrow = mw + (m * 64 + o) * 128;
    const float* cfb  = cf + b * 128;
    float s = 0.f;
#pragma unroll 8
    for (int c = 0; c < 128; ++c) s = fmaf(cfb[c], wrow[c], s);
    mod[(m * 4 + b) * 64 + o] = s * 0.08838834764831845f /*1/sqrt(128)*/ + mb[m * 64 + o];
}

// --- generic tiled 3x3 conv, pad=1, stride=1.
// 32x32 spatial tile, 256 threads: thread = (x = tid&31, rows ybase+8k).
// Input staged in LDS per ICCHUNK channels with (wscale * cond[b,ic]) folded in.
// Weights staged [ic][tap][oc] (wave-uniform broadcast reads).
// SHUF: write pixel-shuffle(2) output layout directly.
// RESID: out[idx] = acc + resid[idx]  (resid may alias out; same-thread RAW only)
template <int CIN, int ICCHUNK, int OCPB, bool RELU, bool RESID, bool SHUF>
__global__ __launch_bounds__(256) void conv3x3_kernel(
    const float* __restrict__ in,    // [B, CIN, H, W]
    const float* __restrict__ wgt,   // [Cout, CIN, 3, 3]
    const float* __restrict__ bias,  // [Cout]
    const float* __restrict__ cond,  // [B*CIN] or nullptr
    const float* resid,              // same layout as out (non-shuf) or nullptr
    float* out,
    int H, int W, int Cout, float wscale)
{
    __shared__ float slds[ICCHUNK][34][35];       // row stride 35: 2-way banks max
    __shared__ float wlds[ICCHUNK * 9 * OCPB];

    const int tid   = threadIdx.x;
    const int x     = tid & 31;
    const int ybase = tid >> 5;                    // 0..7 ; rows = ybase + 8k
    const int OCG   = (Cout + OCPB - 1) / OCPB;
    const int b     = blockIdx.z / OCG;
    const int ocbase = (blockIdx.z % OCG) * OCPB;
    const int tileY = blockIdx.y * 32;
    const int tileX = blockIdx.x * 32;

    float acc[OCPB][4];
#pragma unroll
    for (int oc = 0; oc < OCPB; ++oc)
#pragma unroll
        for (int k = 0; k < 4; ++k) acc[oc][k] = 0.f;

    for (int ic0 = 0; ic0 < CIN; ic0 += ICCHUNK) {
        // stage input tile (with halo, zero-padded) * per-channel scale
        constexpr int NP = ICCHUNK * 34 * 34;
        for (int idx = tid; idx < NP; idx += 256) {
            int ic = idx / (34 * 34);
            int p  = idx % (34 * 34);
            int r = p / 34, c = p % 34;
            int gy = tileY + r - 1, gx = tileX + c - 1;
            float v = 0.f;
            if (gy >= 0 && gy < H && gx >= 0 && gx < W)
                v = in[((b * CIN + ic0 + ic) * H + gy) * W + gx];
            float sc = wscale;
            if (cond) sc *= cond[b * CIN + ic0 + ic];
            slds[ic][r][c] = v * sc;
        }
        // stage weights as [ic][tap][oc]
        constexpr int NW = ICCHUNK * 9 * OCPB;
        for (int idx = tid; idx < NW; idx += 256) {
            int oc  = idx % OCPB;
            int tap = (idx / OCPB) % 9;
            int ic  = idx / (OCPB * 9);
            int goc = ocbase + oc;
            wlds[idx] = (goc < Cout) ? wgt[((goc) * CIN + ic0 + ic) * 9 + tap] : 0.f;
        }
        __syncthreads();

#pragma unroll 2
        for (int ic = 0; ic < ICCHUNK; ++ic) {
#pragma unroll
            for (int dy = 0; dy < 3; ++dy) {
#pragma unroll
                for (int dx = 0; dx < 3; ++dx) {
                    float xv[4];
#pragma unroll
                    for (int k = 0; k < 4; ++k)
                        xv[k] = slds[ic][ybase + 8 * k + dy][x + dx];
                    const float* wrow = &wlds[(ic * 9 + dy * 3 + dx) * OCPB];
#pragma unroll
                    for (int oc = 0; oc < OCPB; ++oc) {
                        float wv = wrow[oc];
#pragma unroll
                        for (int k = 0; k < 4; ++k)
                            acc[oc][k] = fmaf(wv, xv[k], acc[oc][k]);
                    }
                }
            }
        }
        __syncthreads();
    }

    // epilogue
#pragma unroll
    for (int oc = 0; oc < OCPB; ++oc) {
        int goc = ocbase + oc;
        if (goc >= Cout) break;
        float bv = bias[goc];
#pragma unroll
        for (int k = 0; k < 4; ++k) {
            int gy = tileY + ybase + 8 * k;
            int gx = tileX + x;
            float v = acc[oc][k] + bv;
            if (RELU) v = fmaxf(v, 0.f);
            if (!SHUF) {
                int idx = ((b * Cout + goc) * H + gy) * W + gx;
                if (RESID) v += resid[idx];
                out[idx] = v;
            } else {
                int C4 = Cout >> 2;
                int cc = goc >> 2, rr = (goc >> 1) & 1, ss = goc & 1;
                int idx = ((b * C4 + cc) * (2 * H) + (2 * gy + rr)) * (2 * W) + (2 * gx + ss);
                out[idx] = v;
            }
        }
    }
}

extern "C" void kernel_launch(void* const* d_in, const int* in_sizes, int n_in,
                              void* d_out, int out_size, void* d_ws, size_t ws_size,
                              hipStream_t stream) {
    const float* x     = (const float*)d_in[0];
    const float* cf    = (const float*)d_in[1];
    const float* in_w  = (const float*)d_in[2];
    const float* in_b  = (const float*)d_in[3];
    const float* blk_w = (const float*)d_in[4];
    const float* blk_b = (const float*)d_in[5];
    const float* mod_w = (const float*)d_in[6];
    const float* mod_b = (const float*)d_in[7];
    const float* up_w  = (const float*)d_in[8];
    const float* up_b  = (const float*)d_in[9];
    const float* out_w = (const float*)d_in[10];
    const float* out_b = (const float*)d_in[11];
    float* outp = (float*)d_out;

    float *bufA, *bufB, *bufC, *bufE, *modp;
    hipGetSymbolAddress((void**)&bufA, HIP_SYMBOL(g_bufA));
    hipGetSymbolAddress((void**)&bufB, HIP_SYMBOL(g_bufB));
    hipGetSymbolAddress((void**)&bufC, HIP_SYMBOL(g_bufC));
    hipGetSymbolAddress((void**)&bufE, HIP_SYMBOL(g_bufE));
    hipGetSymbolAddress((void**)&modp, HIP_SYMBOL(g_mod));

    const float s_in = 0.19245008972987526f;  // 1/sqrt(3*9)
    const float s64  = 1.0f / 24.0f;          // 1/sqrt(64*9)

    // modulations: 20 x [4,64]
    mod_kernel<<<dim3(20, 4), 64, 0, stream>>>(cf, mod_w, mod_b, modp);

    // input conv: x[4,3,128,128] -> bufA[4,64,128,128]
    conv3x3_kernel<3, 3, 16, false, false, false>
        <<<dim3(4, 4, 16), 256, 0, stream>>>(x, in_w, in_b, nullptr, nullptr,
                                             bufA, 128, 128, 64, s_in);

    // 10 residual blocks
    for (int i = 0; i < 10; ++i) {
        conv3x3_kernel<64, 8, 8, true, false, false>
            <<<dim3(4, 4, 32), 256, 0, stream>>>(
                bufA, blk_w + (size_t)(2 * i) * 64 * 64 * 9, blk_b + (2 * i) * 64,
                modp + (2 * i) * 4 * 64, nullptr, bufB, 128, 128, 64, s64);
        conv3x3_kernel<64, 8, 8, false, true, false>
            <<<dim3(4, 4, 32), 256, 0, stream>>>(
                bufB, blk_w + (size_t)(2 * i + 1) * 64 * 64 * 9, blk_b + (2 * i + 1) * 64,
                modp + (2 * i + 1) * 4 * 64, bufA, bufA, 128, 128, 64, s64);
    }

    // upsample stage 0: bufA[4,64,128,128] -> conv 64->256 -> shuffle -> bufC[4,64,256,256]
    conv3x3_kernel<64, 8, 16, false, false, true>
        <<<dim3(4, 4, 64), 256, 0, stream>>>(bufA, up_w, up_b, nullptr, nullptr,
                                             bufC, 128, 128, 256, s64);
    // upsample stage 1: bufC -> conv 64->256 -> shuffle -> bufE[4,64,512,512]
    conv3x3_kernel<64, 8, 16, false, false, true>
        <<<dim3(8, 8, 64), 256, 0, stream>>>(bufC, up_w + 256 * 64 * 9, up_b + 256,
                                             nullptr, nullptr, bufE, 256, 256, 256, s64);
    // output conv: bufE[4,64,512,512] -> out[4,3,512,512]
    conv3x3_kernel<64, 8, 4, false, false, false>
        <<<dim3(16, 16, 4), 256, 0, stream>>>(bufE, out_w, out_b, nullptr, nullptr,
                                              outp, 512, 512, 3, s64);
}

// Round 2
// 1885.843 us; speedup vs baseline: 3.0239x; 3.0239x over previous
//
#include <hip/hip_runtime.h>
#include <math.h>

typedef unsigned short u16;
typedef unsigned int u32;
typedef float f32x4 __attribute__((ext_vector_type(4)));
typedef short bf16x8 __attribute__((ext_vector_type(8)));
typedef unsigned int u32x4 __attribute__((ext_vector_type(4)));
typedef unsigned short u16x4 __attribute__((ext_vector_type(4)));

// ---------------------------------------------------------------------------
// Activations: channel-last bf16 hi/lo pairs: [b][y][x][k], k in [0,64)=hi,
// [64,128)=lo.  3-term split GEMM: x*w = xhi*whi + xlo*whi + xhi*wlo.
// Weights pre-split per (layer,batch) with modulation folded in (exact).
// ---------------------------------------------------------------------------

__device__ u16 g_bufA[(size_t)4*128*128*128];   // fea ping (ch-last hi/lo)
__device__ u16 g_bufB[(size_t)4*128*128*128];   // fea pong
__device__ u16 g_bufC[(size_t)4*256*256*128];   // after up0 (shuffled)
__device__ u16 g_bufE[(size_t)4*512*512*128];   // after up1 (shuffled)
__device__ float g_mod[20*4*64];
// frag-ordered weights: [(ly*4+b) | (st*4+ocg)][tap9][ck4][mt4][lane64][8]
__device__ u16 g_wblk[(size_t)20*4*73728];
__device__ u16 g_wup[(size_t)2*4*73728];

__device__ inline u16 f2bf(float f) {
    u32 u = __float_as_uint(f);
    u += 0x7fff + ((u >> 16) & 1);
    return (u16)(u >> 16);
}
__device__ inline float bf2f(u16 h) { return __uint_as_float(((u32)h) << 16); }

// --- modulation feats: mod[(m*4+b)*64+o] = s_lin * cf[b,:]·mw[m,o,:] + mb[m,o]
__global__ void mod_kernel(const float* __restrict__ cf,
                           const float* __restrict__ mw,
                           const float* __restrict__ mb,
                           float* __restrict__ mod) {
    int m = blockIdx.x, b = blockIdx.y, o = threadIdx.x;
    const float* wrow = mw + (m * 64 + o) * 128;
    const float* cfb  = cf + b * 128;
    float s = 0.f;
#pragma unroll 8
    for (int c = 0; c < 128; ++c) s = fmaf(cfb[c], wrow[c], s);
    mod[(m * 4 + b) * 64 + o] = s * 0.08838834764831845f + mb[m * 64 + o];
}

// --- weight prep (block convs): frag-blob layout, cond folded, hi/lo split.
// k-space: ck0,1 = whi(ic 0..63), ck2,3 = wlo(ic 0..63)
__global__ void prep_blk_kernel(const float* __restrict__ bw,
                                const float* __restrict__ mod,
                                u16* __restrict__ wp) {
    int ly = blockIdx.x, b = blockIdx.y;
    const float s64 = 1.0f / 24.0f;
    size_t base = (size_t)(ly * 4 + b) * 73728;
    for (int idx = threadIdx.x; idx < 73728; idx += 256) {
        int j = idx & 7, l = (idx >> 3) & 63, mt = (idx >> 9) & 3,
            ck = (idx >> 11) & 3, tap = idx >> 13;
        int m = mt * 16 + (l & 15);
        int k = ck * 32 + (l >> 4) * 8 + j;
        int ic = k & 63, part = k >> 6;
        float val = bw[((size_t)(ly * 64 + m) * 64 + ic) * 9 + tap] * s64 *
                    mod[(ly * 4 + b) * 64 + ic];
        u16 hi = f2bf(val);
        wp[base + idx] = part ? f2bf(val - bf2f(hi)) : hi;
    }
}

__global__ void prep_up_kernel(const float* __restrict__ uw, u16* __restrict__ wp) {
    int st = blockIdx.x, ocg = blockIdx.y;
    const float s64 = 1.0f / 24.0f;
    size_t base = (size_t)(st * 4 + ocg) * 73728;
    for (int idx = threadIdx.x; idx < 73728; idx += 256) {
        int j = idx & 7, l = (idx >> 3) & 63, mt = (idx >> 9) & 3,
            ck = (idx >> 11) & 3, tap = idx >> 13;
        int o = ocg * 64 + mt * 16 + (l & 15);
        int k = ck * 32 + (l >> 4) * 8 + j;
        int ic = k & 63, part = k >> 6;
        float val = uw[((size_t)(st * 256 + o) * 64 + ic) * 9 + tap] * s64;
        u16 hi = f2bf(val);
        wp[base + idx] = part ? f2bf(val - bf2f(hi)) : hi;
    }
}

// --- input conv (3->64, 128x128, fp32 scalar), writes ch-last hi/lo
__global__ __launch_bounds__(256) void in_conv_kernel(
    const float* __restrict__ in, const float* __restrict__ wgt,
    const float* __restrict__ bias, u16* __restrict__ out) {
    __shared__ float slds[3][34][35];
    __shared__ float wlds[3 * 9 * 16];
    const int H = 128, W = 128;
    const int tid = threadIdx.x, x = tid & 31, yb = tid >> 5;
    const int b = blockIdx.z >> 2, ocb = (blockIdx.z & 3) * 16;
    const int tY = blockIdx.y * 32, tX = blockIdx.x * 32;
    const float s_in = 0.19245008972987526f;

    float acc[16][4];
#pragma unroll
    for (int oc = 0; oc < 16; ++oc)
#pragma unroll
        for (int k = 0; k < 4; ++k) acc[oc][k] = 0.f;

    for (int idx = tid; idx < 3 * 34 * 34; idx += 256) {
        int ic = idx / (34 * 34), p = idx % (34 * 34);
        int r = p / 34, c = p % 34;
        int gy = tY + r - 1, gx = tX + c - 1;
        float v = 0.f;
        if (gy >= 0 && gy < H && gx >= 0 && gx < W)
            v = in[((b * 3 + ic) * H + gy) * W + gx] * s_in;
        slds[ic][r][c] = v;
    }
    for (int idx = tid; idx < 3 * 9 * 16; idx += 256) {
        int oc = idx & 15, tap = (idx >> 4) % 9, ic = idx / 144;
        wlds[idx] = wgt[((ocb + oc) * 3 + ic) * 9 + tap];
    }
    __syncthreads();

#pragma unroll
    for (int ic = 0; ic < 3; ++ic)
#pragma unroll
        for (int dy = 0; dy < 3; ++dy)
#pragma unroll
            for (int dx = 0; dx < 3; ++dx) {
                float xv[4];
#pragma unroll
                for (int k = 0; k < 4; ++k)
                    xv[k] = slds[ic][yb + 8 * k + dy][x + dx];
                const float* wrow = &wlds[(ic * 9 + dy * 3 + dx) * 16];
#pragma unroll
                for (int oc = 0; oc < 16; ++oc) {
                    float wv = wrow[oc];
#pragma unroll
                    for (int k = 0; k < 4; ++k) acc[oc][k] = fmaf(wv, xv[k], acc[oc][k]);
                }
            }

#pragma unroll
    for (int oc = 0; oc < 16; ++oc) {
        int goc = ocb + oc;
        float bv = bias[goc];
#pragma unroll
        for (int k = 0; k < 4; ++k) {
            int gy = tY + yb + 8 * k, gx = tX + x;
            float v = acc[oc][k] + bv;
            u16 hi = f2bf(v);
            u16 lo = f2bf(v - bf2f(hi));
            size_t pixG = ((size_t)b * H + gy) * W + gx;
            out[pixG * 128 + goc] = hi;
            out[pixG * 128 + 64 + goc] = lo;
        }
    }
}

// --- MFMA conv: Cin=64, Cout=64 per block (ocg picks the 64-slice).
// Tile 16x16 px, 4 waves; wave owns 4 rows x all 4 M-frags.
// B: LDS ch-last, XOR-swizzled; A: per-tap frag blobs, double-buffered LDS.
template <bool RELU, bool RESID, bool SHUF>
__global__ __launch_bounds__(256, 1) void mconv_kernel(
    const u16* __restrict__ in, const u16* __restrict__ wp,
    const float* __restrict__ bias, const u16* resid, u16* __restrict__ out,
    int H, int W, int OCG, int wp_bstride) {
    __shared__ u16 sB[18 * 18 * 128];   // 82944 B
    __shared__ u16 sA[2 * 16 * 512];    // 32768 B

    const int tid = threadIdx.x;
    const int lane = tid & 63, wv = tid >> 6;
    const int lcol = lane & 15, lk8 = lane >> 4;
    const int b = blockIdx.z / OCG, ocg = blockIdx.z % OCG;
    const int y0 = blockIdx.y * 16, x0 = blockIdx.x * 16;
    const u16* wpb = wp + (size_t)b * wp_bstride + (size_t)ocg * 73728;

    // stage B tile (18x18 px, halo, zero-pad) with chunk XOR swizzle
    for (int idx = tid; idx < 324 * 16; idx += 256) {
        int pixL = idx >> 4, c = idx & 15;
        int r = pixL / 18, xx = pixL - r * 18;
        int gy = y0 + r - 1, gx = x0 + xx - 1;
        u32x4 v = (u32x4)0;
        if (gy >= 0 && gy < H && gx >= 0 && gx < W)
            v = *(const u32x4*)(in + (((size_t)b * H + gy) * W + gx) * 128 + c * 8);
        *(u32x4*)(sB + pixL * 128 + ((c ^ (pixL & 7)) * 8)) = v;
    }
    // stage A tap 0
    u32x4 areg[4];
#pragma unroll
    for (int i = 0; i < 4; ++i) {
        int f = i * 4 + wv;
        areg[i] = *(const u32x4*)(wpb + (size_t)f * 512 + lane * 8);
    }
    __syncthreads();
#pragma unroll
    for (int i = 0; i < 4; ++i) {
        int f = i * 4 + wv;
        *(u32x4*)(sA + f * 512 + lane * 8) = areg[i];
    }
    __syncthreads();

    f32x4 acc[4][4];
#pragma unroll
    for (int mt = 0; mt < 4; ++mt)
#pragma unroll
        for (int nf = 0; nf < 4; ++nf) acc[mt][nf] = (f32x4)0.f;

    for (int tap = 0; tap < 9; ++tap) {
        const int cur = tap & 1;
        const int dy = tap / 3, dx = tap - dy * 3;
        if (tap < 8) {
#pragma unroll
            for (int i = 0; i < 4; ++i) {
                int f = i * 4 + wv;
                areg[i] = *(const u32x4*)(wpb + ((size_t)(tap + 1) * 16 + f) * 512 + lane * 8);
            }
        }
        const u16* pa = sA + cur * 8192 + lane * 8;
        bf16x8 a0[4], a1[4], at[4], b0[4], b1[4], bt[4];

#pragma unroll
        for (int nf = 0; nf < 4; ++nf) {
            int pixL = (wv * 4 + nf + dy) * 18 + lcol + dx;
            const u16* pb = sB + pixL * 128;
            int sw = pixL & 7;
            b0[nf] = *(const bf16x8*)(pb + (((0 * 4 + lk8) ^ sw) * 8));
            b1[nf] = *(const bf16x8*)(pb + (((1 * 4 + lk8) ^ sw) * 8));
        }
#pragma unroll
        for (int mt = 0; mt < 4; ++mt) a0[mt] = *(const bf16x8*)(pa + (0 * 4 + mt) * 512);
#pragma unroll
        for (int mt = 0; mt < 4; ++mt)
#pragma unroll
            for (int nf = 0; nf < 4; ++nf)
                acc[mt][nf] = __builtin_amdgcn_mfma_f32_16x16x32_bf16(a0[mt], b0[nf], acc[mt][nf], 0, 0, 0);
#pragma unroll
        for (int mt = 0; mt < 4; ++mt) a1[mt] = *(const bf16x8*)(pa + (1 * 4 + mt) * 512);
#pragma unroll
        for (int mt = 0; mt < 4; ++mt)
#pragma unroll
            for (int nf = 0; nf < 4; ++nf)
                acc[mt][nf] = __builtin_amdgcn_mfma_f32_16x16x32_bf16(a1[mt], b1[nf], acc[mt][nf], 0, 0, 0);
#pragma unroll
        for (int nf = 0; nf < 4; ++nf) {
            int pixL = (wv * 4 + nf + dy) * 18 + lcol + dx;
            bt[nf] = *(const bf16x8*)(sB + pixL * 128 + (((2 * 4 + lk8) ^ (pixL & 7)) * 8));
        }
#pragma unroll
        for (int mt = 0; mt < 4; ++mt)
#pragma unroll
            for (int nf = 0; nf < 4; ++nf)
                acc[mt][nf] = __builtin_amdgcn_mfma_f32_16x16x32_bf16(a0[mt], bt[nf], acc[mt][nf], 0, 0, 0);
#pragma unroll
        for (int nf = 0; nf < 4; ++nf) {
            int pixL = (wv * 4 + nf + dy) * 18 + lcol + dx;
            bt[nf] = *(const bf16x8*)(sB + pixL * 128 + (((3 * 4 + lk8) ^ (pixL & 7)) * 8));
        }
#pragma unroll
        for (int mt = 0; mt < 4; ++mt)
#pragma unroll
            for (int nf = 0; nf < 4; ++nf)
                acc[mt][nf] = __builtin_amdgcn_mfma_f32_16x16x32_bf16(a1[mt], bt[nf], acc[mt][nf], 0, 0, 0);
#pragma unroll
        for (int mt = 0; mt < 4; ++mt) at[mt] = *(const bf16x8*)(pa + (2 * 4 + mt) * 512);
#pragma unroll
        for (int mt = 0; mt < 4; ++mt)
#pragma unroll
            for (int nf = 0; nf < 4; ++nf)
                acc[mt][nf] = __builtin_amdgcn_mfma_f32_16x16x32_bf16(at[mt], b0[nf], acc[mt][nf], 0, 0, 0);
#pragma unroll
        for (int mt = 0; mt < 4; ++mt) at[mt] = *(const bf16x8*)(pa + (3 * 4 + mt) * 512);
#pragma unroll
        for (int mt = 0; mt < 4; ++mt)
#pragma unroll
            for (int nf = 0; nf < 4; ++nf)
                acc[mt][nf] = __builtin_amdgcn_mfma_f32_16x16x32_bf16(at[mt], b1[nf], acc[mt][nf], 0, 0, 0);

        if (tap < 8) {
            int nxt = cur ^ 1;
#pragma unroll
            for (int i = 0; i < 4; ++i) {
                int f = i * 4 + wv;
                *(u32x4*)(sA + nxt * 8192 + f * 512 + lane * 8) = areg[i];
            }
        }
        __syncthreads();
    }

    // epilogue: C/D frag: col(pixel)=lane&15, row(m)=(lane>>4)*4+reg
#pragma unroll
    for (int mt = 0; mt < 4; ++mt) {
        int m0 = mt * 16 + lk8 * 4;
        int goc0 = ocg * 64 + m0;
#pragma unroll
        for (int nf = 0; nf < 4; ++nf) {
            int gy = y0 + wv * 4 + nf, gx = x0 + lcol;
            size_t pixG = ((size_t)b * H + gy) * W + gx;
            float v[4];
#pragma unroll
            for (int j = 0; j < 4; ++j) {
                v[j] = acc[mt][nf][j] + bias[goc0 + j];
                if (RELU) v[j] = fmaxf(v[j], 0.f);
            }
            if (RESID) {
                u16x4 rh = *(const u16x4*)(resid + pixG * 128 + m0);
                u16x4 rl = *(const u16x4*)(resid + pixG * 128 + 64 + m0);
#pragma unroll
                for (int j = 0; j < 4; ++j) v[j] += bf2f(rh[j]) + bf2f(rl[j]);
            }
            if (!SHUF) {
                u16x4 hs, ls;
#pragma unroll
                for (int j = 0; j < 4; ++j) {
                    hs[j] = f2bf(v[j]);
                    ls[j] = f2bf(v[j] - bf2f(hs[j]));
                }
                *(u16x4*)(out + pixG * 128 + m0) = hs;
                *(u16x4*)(out + pixG * 128 + 64 + m0) = ls;
            } else {
#pragma unroll
                for (int j = 0; j < 4; ++j) {
                    int goc = goc0 + j;
                    int cc = goc >> 2, r0 = (goc >> 1) & 1, r1 = goc & 1;
                    size_t opix = ((size_t)b * (2 * H) + 2 * gy + r0) * (size_t)(2 * W) + 2 * gx + r1;
                    u16 hi = f2bf(v[j]);
                    u16 lo = f2bf(v[j] - bf2f(hi));
                    out[opix * 128 + cc] = hi;
                    out[opix * 128 + 64 + cc] = lo;
                }
            }
        }
    }
}

// --- output conv (64->3, 512x512, fp32 scalar), ch-last hi/lo input
__global__ __launch_bounds__(256) void out_conv_kernel(
    const u16* __restrict__ in, const float* __restrict__ wgt,
    const float* __restrict__ bias, float* __restrict__ out) {
    __shared__ float slds[8][34][35];
    __shared__ float wlds[8 * 9 * 4];
    const int H = 512, W = 512;
    const int tid = threadIdx.x, x = tid & 31, yb = tid >> 5;
    const int b = blockIdx.z;
    const int tY = blockIdx.y * 32, tX = blockIdx.x * 32;
    const float s64 = 1.0f / 24.0f;

    float acc[3][4];
#pragma unroll
    for (int oc = 0; oc < 3; ++oc)
#pragma unroll
        for (int k = 0; k < 4; ++k) acc[oc][k] = 0.f;

    for (int ic0 = 0; ic0 < 64; ic0 += 8) {
        for (int idx = tid; idx < 34 * 34 * 8; idx += 256) {
            int ic = idx & 7, pix = idx >> 3;
            int r = pix / 34, c = pix - r * 34;
            int gy = tY + r - 1, gx = tX + c - 1;
            float v = 0.f;
            if (gy >= 0 && gy < H && gx >= 0 && gx < W) {
                size_t pg = (((size_t)b * H + gy) * W + gx) * 128 + ic0 + ic;
                v = bf2f(in[pg]) + bf2f(in[pg + 64]);
            }
            slds[ic][r][c] = v;
        }
        for (int idx = tid; idx < 8 * 9 * 4; idx += 256) {
            int oc = idx & 3, tap = (idx >> 2) % 9, ic = idx / 36;
            wlds[idx] = (oc < 3) ? wgt[((oc * 64) + ic0 + ic) * 9 + tap] * s64 : 0.f;
        }
        __syncthreads();
#pragma unroll 2
        for (int ic = 0; ic < 8; ++ic)
#pragma unroll
            for (int dy = 0; dy < 3; ++dy)
#pragma unroll
                for (int dx = 0; dx < 3; ++dx) {
                    float xv[4];
#pragma unroll
                    for (int k = 0; k < 4; ++k)
                        xv[k] = slds[ic][yb + 8 * k + dy][x + dx];
                    const float* wrow = &wlds[(ic * 9 + dy * 3 + dx) * 4];
#pragma unroll
                    for (int oc = 0; oc < 3; ++oc) {
                        float wv = wrow[oc];
#pragma unroll
                        for (int k = 0; k < 4; ++k) acc[oc][k] = fmaf(wv, xv[k], acc[oc][k]);
                    }
                }
        __syncthreads();
    }
#pragma unroll
    for (int oc = 0; oc < 3; ++oc) {
        float bv = bias[oc];
#pragma unroll
        for (int k = 0; k < 4; ++k) {
            int gy = tY + yb + 8 * k, gx = tX + x;
            out[(((size_t)b * 3 + oc) * H + gy) * W + gx] = acc[oc][k] + bv;
        }
    }
}

extern "C" void kernel_launch(void* const* d_in, const int* in_sizes, int n_in,
                              void* d_out, int out_size, void* d_ws, size_t ws_size,
                              hipStream_t stream) {
    const float* x     = (const float*)d_in[0];
    const float* cf    = (const float*)d_in[1];
    const float* in_w  = (const float*)d_in[2];
    const float* in_b  = (const float*)d_in[3];
    const float* blk_w = (const float*)d_in[4];
    const float* blk_b = (const float*)d_in[5];
    const float* mod_w = (const float*)d_in[6];
    const float* mod_b = (const float*)d_in[7];
    const float* up_w  = (const float*)d_in[8];
    const float* up_b  = (const float*)d_in[9];
    const float* out_w = (const float*)d_in[10];
    const float* out_b = (const float*)d_in[11];
    float* outp = (float*)d_out;

    u16 *bufA, *bufB, *bufC, *bufE, *wblk, *wup;
    float* modp;
    hipGetSymbolAddress((void**)&bufA, HIP_SYMBOL(g_bufA));
    hipGetSymbolAddress((void**)&bufB, HIP_SYMBOL(g_bufB));
    hipGetSymbolAddress((void**)&bufC, HIP_SYMBOL(g_bufC));
    hipGetSymbolAddress((void**)&bufE, HIP_SYMBOL(g_bufE));
    hipGetSymbolAddress((void**)&modp, HIP_SYMBOL(g_mod));
    hipGetSymbolAddress((void**)&wblk, HIP_SYMBOL(g_wblk));
    hipGetSymbolAddress((void**)&wup,  HIP_SYMBOL(g_wup));

    mod_kernel<<<dim3(20, 4), 64, 0, stream>>>(cf, mod_w, mod_b, modp);
    prep_blk_kernel<<<dim3(20, 4), 256, 0, stream>>>(blk_w, modp, wblk);
    prep_up_kernel<<<dim3(2, 4), 256, 0, stream>>>(up_w, wup);

    in_conv_kernel<<<dim3(4, 4, 16), 256, 0, stream>>>(x, in_w, in_b, bufA);

    for (int i = 0; i < 10; ++i) {
        mconv_kernel<true, false, false><<<dim3(8, 8, 4), 256, 0, stream>>>(
            bufA, wblk + (size_t)(2 * i) * 4 * 73728, blk_b + (2 * i) * 64,
            nullptr, bufB, 128, 128, 1, 73728);
        mconv_kernel<false, true, false><<<dim3(8, 8, 4), 256, 0, stream>>>(
            bufB, wblk + (size_t)(2 * i + 1) * 4 * 73728, blk_b + (2 * i + 1) * 64,
            bufA, bufA, 128, 128, 1, 73728);
    }

    // up0: 64->256 @128^2, shuffle -> bufC (256^2)
    mconv_kernel<false, false, true><<<dim3(8, 8, 16), 256, 0, stream>>>(
        bufA, wup, up_b, nullptr, bufC, 128, 128, 4, 0);
    // up1: 64->256 @256^2, shuffle -> bufE (512^2)
    mconv_kernel<false, false, true><<<dim3(16, 16, 16), 256, 0, stream>>>(
        bufC, wup + (size_t)4 * 73728, up_b + 256, nullptr, bufE, 256, 256, 4, 0);

    out_conv_kernel<<<dim3(16, 16, 4), 256, 0, stream>>>(bufE, out_w, out_b, outp);
}

// Round 3
// 1283.673 us; speedup vs baseline: 4.4424x; 1.4691x over previous
//
#include <hip/hip_runtime.h>
#include <math.h>

typedef unsigned short u16;
typedef unsigned int u32;
typedef float f32x4 __attribute__((ext_vector_type(4)));
typedef short bf16x8 __attribute__((ext_vector_type(8)));
typedef unsigned int u32x4 __attribute__((ext_vector_type(4)));
typedef unsigned short u16x4 __attribute__((ext_vector_type(4)));
typedef float f32x2 __attribute__((ext_vector_type(2)));

// ---------------------------------------------------------------------------
// Activations: channel-last bf16 hi/lo pairs [b][y][x][128] (0-63 hi, 64-127 lo)
// 3-term split: x*w = xhi*whi + xlo*whi + xhi*wlo (exact to ~2^-18)
// Weights pre-split per (layer,batch) frag blobs, modulation folded in.
// mconv: A (weights) global->reg, B (pixels) LDS; row-structured tap reuse.
// ---------------------------------------------------------------------------

__device__ u16 g_bufA[(size_t)4*128*128*128];
__device__ u16 g_bufB[(size_t)4*128*128*128];
__device__ u16 g_bufC[(size_t)4*256*256*128];    // up0 out (shuffled, bf16 hi/lo)
__device__ float g_bufE[(size_t)4*512*512*64];   // up1 out (shuffled, fp32 ch-last)
__device__ float g_mod[20*4*64];
// frag blobs: [(ly*4+b) | (st*4+ocg)][tap9][ck4][mt4][lane64][8]
__device__ u16 g_wblk[(size_t)20*4*73728];
__device__ u16 g_wup[(size_t)2*4*73728];

__device__ inline u16 f2bf(float f) {
    u32 u = __float_as_uint(f);
    u += 0x7fff + ((u >> 16) & 1);
    return (u16)(u >> 16);
}
__device__ inline float bf2f(u16 h) { return __uint_as_float(((u32)h) << 16); }

__global__ void mod_kernel(const float* __restrict__ cf,
                           const float* __restrict__ mw,
                           const float* __restrict__ mb,
                           float* __restrict__ mod) {
    int m = blockIdx.x, b = blockIdx.y, o = threadIdx.x;
    const float* wrow = mw + (m * 64 + o) * 128;
    const float* cfb  = cf + b * 128;
    float s = 0.f;
#pragma unroll 8
    for (int c = 0; c < 128; ++c) s = fmaf(cfb[c], wrow[c], s);
    mod[(m * 4 + b) * 64 + o] = s * 0.08838834764831845f + mb[m * 64 + o];
}

// k-space per blob: ck0,1 = whi(ic 0-31,32-63); ck2,3 = wlo(ic 0-31,32-63)
__global__ void prep_blk_kernel(const float* __restrict__ bw,
                                const float* __restrict__ mod,
                                u16* __restrict__ wp) {
    int ly = blockIdx.x, b = blockIdx.y;
    const float s64 = 1.0f / 24.0f;
    size_t base = (size_t)(ly * 4 + b) * 73728;
    for (int idx = threadIdx.x; idx < 73728; idx += 256) {
        int j = idx & 7, l = (idx >> 3) & 63, mt = (idx >> 9) & 3,
            ck = (idx >> 11) & 3, tap = idx >> 13;
        int m = mt * 16 + (l & 15);
        int k = ck * 32 + (l >> 4) * 8 + j;
        int ic = k & 63, part = k >> 6;
        float val = bw[((size_t)(ly * 64 + m) * 64 + ic) * 9 + tap] * s64 *
                    mod[(ly * 4 + b) * 64 + ic];
        u16 hi = f2bf(val);
        wp[base + idx] = part ? f2bf(val - bf2f(hi)) : hi;
    }
}

__global__ void prep_up_kernel(const float* __restrict__ uw, u16* __restrict__ wp) {
    int st = blockIdx.x, ocg = blockIdx.y;
    const float s64 = 1.0f / 24.0f;
    size_t base = (size_t)(st * 4 + ocg) * 73728;
    for (int idx = threadIdx.x; idx < 73728; idx += 256) {
        int j = idx & 7, l = (idx >> 3) & 63, mt = (idx >> 9) & 3,
            ck = (idx >> 11) & 3, tap = idx >> 13;
        int o = ocg * 64 + mt * 16 + (l & 15);
        int k = ck * 32 + (l >> 4) * 8 + j;
        int ic = k & 63, part = k >> 6;
        float val = uw[((size_t)(st * 256 + o) * 64 + ic) * 9 + tap] * s64;
        u16 hi = f2bf(val);
        wp[base + idx] = part ? f2bf(val - bf2f(hi)) : hi;
    }
}

// --- input conv (3->64, fp32 scalar), writes ch-last hi/lo
__global__ __launch_bounds__(256) void in_conv_kernel(
    const float* __restrict__ in, const float* __restrict__ wgt,
    const float* __restrict__ bias, u16* __restrict__ out) {
    __shared__ float slds[3][34][35];
    __shared__ float wlds[3 * 9 * 16];
    const int H = 128, W = 128;
    const int tid = threadIdx.x, x = tid & 31, yb = tid >> 5;
    const int b = blockIdx.z >> 2, ocb = (blockIdx.z & 3) * 16;
    const int tY = blockIdx.y * 32, tX = blockIdx.x * 32;
    const float s_in = 0.19245008972987526f;

    float acc[16][4];
#pragma unroll
    for (int oc = 0; oc < 16; ++oc)
#pragma unroll
        for (int k = 0; k < 4; ++k) acc[oc][k] = 0.f;

    for (int idx = tid; idx < 3 * 34 * 34; idx += 256) {
        int ic = idx / (34 * 34), p = idx % (34 * 34);
        int r = p / 34, c = p % 34;
        int gy = tY + r - 1, gx = tX + c - 1;
        float v = 0.f;
        if (gy >= 0 && gy < H && gx >= 0 && gx < W)
            v = in[((b * 3 + ic) * H + gy) * W + gx] * s_in;
        slds[ic][r][c] = v;
    }
    for (int idx = tid; idx < 3 * 9 * 16; idx += 256) {
        int oc = idx & 15, tap = (idx >> 4) % 9, ic = idx / 144;
        wlds[idx] = wgt[((ocb + oc) * 3 + ic) * 9 + tap];
    }
    __syncthreads();

#pragma unroll
    for (int ic = 0; ic < 3; ++ic)
#pragma unroll
        for (int dy = 0; dy < 3; ++dy)
#pragma unroll
            for (int dx = 0; dx < 3; ++dx) {
                float xv[4];
#pragma unroll
                for (int k = 0; k < 4; ++k)
                    xv[k] = slds[ic][yb + 8 * k + dy][x + dx];
                const float* wrow = &wlds[(ic * 9 + dy * 3 + dx) * 16];
#pragma unroll
                for (int oc = 0; oc < 16; ++oc) {
                    float wv = wrow[oc];
#pragma unroll
                    for (int k = 0; k < 4; ++k) acc[oc][k] = fmaf(wv, xv[k], acc[oc][k]);
                }
            }

#pragma unroll
    for (int oc = 0; oc < 16; ++oc) {
        int goc = ocb + oc;
        float bv = bias[goc];
#pragma unroll
        for (int k = 0; k < 4; ++k) {
            int gy = tY + yb + 8 * k, gx = tX + x;
            float v = acc[oc][k] + bv;
            u16 hi = f2bf(v);
            u16 lo = f2bf(v - bf2f(hi));
            size_t pixG = ((size_t)b * H + gy) * W + gx;
            out[pixG * 128 + goc] = hi;
            out[pixG * 128 + 64 + goc] = lo;
        }
    }
}

// --- MFMA conv. Tile 16 cols x 8 rows, 4 waves (wave = 2 out rows, 64 oc).
// A: global->reg per dx (A[dy][ck][mt], 36 frags). B: LDS, swizzled, read once
// per (dx,bck,row), reused across dy/mt/terms. No barriers in main loop.
// SHUF: 0 = none (ch-last hi/lo out), 1 = pixelshuffle bf16 hi/lo, 2 = ps fp32
template <bool RELU, bool RESID, int SHUF>
__global__ __launch_bounds__(256, 2) void mconv_kernel(
    const u16* __restrict__ in, const u16* __restrict__ wp,
    const float* __restrict__ bias, const u16* resid, void* outv,
    int H, int W, int OCG, int wp_bstride) {
    __shared__ __align__(16) char smem[46080];
    u16* sB = (u16*)smem;
    float* sT = (float*)smem;   // SHUF transpose buffer [512][18], aliases sB

    const int tid = threadIdx.x;
    const int lane = tid & 63, wv = tid >> 6;
    const int lcol = lane & 15, lk8 = lane >> 4;
    const int b = blockIdx.z / OCG, ocg = blockIdx.z % OCG;
    const int y0 = blockIdx.y * 8, x0 = blockIdx.x * 16;
    const u16* wpb = wp + (size_t)b * wp_bstride + (size_t)ocg * 73728;

    // stage B: 10 halo rows x 18 cols x 16 chunks of 16B, XOR-swizzled
    for (int idx = tid; idx < 180 * 16; idx += 256) {
        int pixL = idx >> 4, c = idx & 15;
        int r = pixL / 18, xx = pixL - r * 18;
        int gy = y0 + r - 1, gx = x0 + xx - 1;
        u32x4 v = (u32x4)0;
        if (gy >= 0 && gy < H && gx >= 0 && gx < W)
            v = *(const u32x4*)(in + (((size_t)b * H + gy) * W + gx) * 128 + c * 8);
        *(u32x4*)(sB + pixL * 128 + ((c ^ (pixL & 7)) * 8)) = v;
    }
    __syncthreads();

    f32x4 acc[4][2];
#pragma unroll
    for (int mt = 0; mt < 4; ++mt)
#pragma unroll
        for (int r = 0; r < 2; ++r) acc[mt][r] = (f32x4)0.f;

#pragma unroll
    for (int dx = 0; dx < 3; ++dx) {
        // A frags for this dx: [dy][ck][mt], from global (L2-resident blob)
        bf16x8 A[3][4][4];
#pragma unroll
        for (int dy = 0; dy < 3; ++dy)
#pragma unroll
            for (int ck = 0; ck < 4; ++ck)
#pragma unroll
                for (int mt = 0; mt < 4; ++mt)
                    A[dy][ck][mt] = *(const bf16x8*)(
                        wpb + (size_t)(((dy * 3 + dx) * 16 + ck * 4 + mt) * 512) + lane * 8);

#pragma unroll
        for (int bck = 0; bck < 4; ++bck) {
#pragma unroll
            for (int R = 0; R < 4; ++R) {
                int pixL = (wv * 2 + R) * 18 + lcol + dx;
                bf16x8 Bf = *(const bf16x8*)(
                    sB + pixL * 128 + (((bck * 4 + lk8) ^ (pixL & 7)) * 8));
#pragma unroll
                for (int dy = 0; dy < 3; ++dy) {
                    int orow = R - dy;
                    if (orow < 0 || orow > 1) continue;
                    if (bck == 0) {
#pragma unroll
                        for (int mt = 0; mt < 4; ++mt)
                            acc[mt][orow] = __builtin_amdgcn_mfma_f32_16x16x32_bf16(A[dy][0][mt], Bf, acc[mt][orow], 0, 0, 0);
#pragma unroll
                        for (int mt = 0; mt < 4; ++mt)
                            acc[mt][orow] = __builtin_amdgcn_mfma_f32_16x16x32_bf16(A[dy][2][mt], Bf, acc[mt][orow], 0, 0, 0);
                    } else if (bck == 1) {
#pragma unroll
                        for (int mt = 0; mt < 4; ++mt)
                            acc[mt][orow] = __builtin_amdgcn_mfma_f32_16x16x32_bf16(A[dy][1][mt], Bf, acc[mt][orow], 0, 0, 0);
#pragma unroll
                        for (int mt = 0; mt < 4; ++mt)
                            acc[mt][orow] = __builtin_amdgcn_mfma_f32_16x16x32_bf16(A[dy][3][mt], Bf, acc[mt][orow], 0, 0, 0);
                    } else if (bck == 2) {
#pragma unroll
                        for (int mt = 0; mt < 4; ++mt)
                            acc[mt][orow] = __builtin_amdgcn_mfma_f32_16x16x32_bf16(A[dy][0][mt], Bf, acc[mt][orow], 0, 0, 0);
                    } else {
#pragma unroll
                        for (int mt = 0; mt < 4; ++mt)
                            acc[mt][orow] = __builtin_amdgcn_mfma_f32_16x16x32_bf16(A[dy][1][mt], Bf, acc[mt][orow], 0, 0, 0);
                    }
                }
            }
        }
    }

    // ---- epilogue. C/D frag: col(pixel)=lane&15, row(oc)=(lane>>4)*4+reg
    if (SHUF == 0) {
        u16* out = (u16*)outv;
#pragma unroll
        for (int mt = 0; mt < 4; ++mt) {
            int m0 = mt * 16 + lk8 * 4;
#pragma unroll
            for (int r = 0; r < 2; ++r) {
                int gy = y0 + wv * 2 + r, gx = x0 + lcol;
                size_t pixG = ((size_t)b * H + gy) * W + gx;
                float v[4];
#pragma unroll
                for (int j = 0; j < 4; ++j) {
                    v[j] = acc[mt][r][j] + bias[m0 + j];
                    if (RELU) v[j] = fmaxf(v[j], 0.f);
                }
                if (RESID) {
                    u16x4 rh = *(const u16x4*)(resid + pixG * 128 + m0);
                    u16x4 rl = *(const u16x4*)(resid + pixG * 128 + 64 + m0);
#pragma unroll
                    for (int j = 0; j < 4; ++j) v[j] += bf2f(rh[j]) + bf2f(rl[j]);
                }
                u16x4 hs, ls;
#pragma unroll
                for (int j = 0; j < 4; ++j) {
                    hs[j] = f2bf(v[j]);
                    ls[j] = f2bf(v[j] - bf2f(hs[j]));
                }
                *(u16x4*)(out + pixG * 128 + m0) = hs;
                *(u16x4*)(out + pixG * 128 + 64 + m0) = ls;
            }
        }
    } else {
        __syncthreads();   // done reading sB; reuse as sT
#pragma unroll
        for (int mt = 0; mt < 4; ++mt) {
            int chl = mt * 4 + lk8;   // local cc
#pragma unroll
            for (int r = 0; r < 2; ++r) {
#pragma unroll
                for (int j = 0; j < 4; ++j) {
                    float v = acc[mt][r][j] + bias[ocg * 64 + mt * 16 + lk8 * 4 + j];
                    int oy = 2 * (wv * 2 + r) + (j >> 1);
                    int ox = 2 * lcol + (j & 1);
                    sT[(oy * 32 + ox) * 18 + chl] = v;
                }
            }
        }
        __syncthreads();
        const int H2 = 2 * H, W2 = 2 * W;
        for (int o = tid; o < 512; o += 256) {
            int oy = o >> 5, ox = o & 31;
            float vals[16];
#pragma unroll
            for (int c = 0; c < 8; ++c) {
                f32x2 t = *(const f32x2*)(sT + o * 18 + c * 2);
                vals[2 * c] = t[0];
                vals[2 * c + 1] = t[1];
            }
            size_t pixO = ((size_t)b * H2 + (2 * y0 + oy)) * W2 + (2 * x0 + ox);
            if (SHUF == 2) {
                float* out = (float*)outv + pixO * 64 + ocg * 16;
#pragma unroll
                for (int c = 0; c < 4; ++c)
                    *(f32x4*)(out + c * 4) = *(f32x4*)(vals + c * 4);
            } else {
                u32 hw[8], lw[8];
#pragma unroll
                for (int i = 0; i < 8; ++i) {
                    u16 h0 = f2bf(vals[2 * i]);
                    u16 l0 = f2bf(vals[2 * i] - bf2f(h0));
                    u16 h1 = f2bf(vals[2 * i + 1]);
                    u16 l1 = f2bf(vals[2 * i + 1] - bf2f(h1));
                    hw[i] = (u32)h0 | ((u32)h1 << 16);
                    lw[i] = (u32)l0 | ((u32)l1 << 16);
                }
                u16* out = (u16*)outv + pixO * 128;
                *(u32x4*)(out + ocg * 16)      = *(u32x4*)(hw);
                *(u32x4*)(out + ocg * 16 + 8)  = *(u32x4*)(hw + 4);
                *(u32x4*)(out + 64 + ocg * 16)     = *(u32x4*)(lw);
                *(u32x4*)(out + 64 + ocg * 16 + 8) = *(u32x4*)(lw + 4);
            }
        }
    }
}

// --- output conv (64->3, 512x512, fp32 scalar), fp32 ch-last input
__global__ __launch_bounds__(256) void out_conv_kernel(
    const float* __restrict__ in, const float* __restrict__ wgt,
    const float* __restrict__ bias, float* __restrict__ out) {
    __shared__ float slds[8][34][35];
    __shared__ float wlds[8 * 9 * 4];
    const int H = 512, W = 512;
    const int tid = threadIdx.x, x = tid & 31, yb = tid >> 5;
    const int b = blockIdx.z;
    const int tY = blockIdx.y * 32, tX = blockIdx.x * 32;
    const float s64 = 1.0f / 24.0f;

    float acc[3][4];
#pragma unroll
    for (int oc = 0; oc < 3; ++oc)
#pragma unroll
        for (int k = 0; k < 4; ++k) acc[oc][k] = 0.f;

    for (int ic0 = 0; ic0 < 64; ic0 += 8) {
        for (int idx = tid; idx < 34 * 34 * 8; idx += 256) {
            int ic = idx & 7, pix = idx >> 3;
            int r = pix / 34, c = pix - r * 34;
            int gy = tY + r - 1, gx = tX + c - 1;
            float v = 0.f;
            if (gy >= 0 && gy < H && gx >= 0 && gx < W)
                v = in[(((size_t)b * H + gy) * W + gx) * 64 + ic0 + ic];
            slds[ic][r][c] = v;
        }
        for (int idx = tid; idx < 8 * 9 * 4; idx += 256) {
            int oc = idx & 3, tap = (idx >> 2) % 9, ic = idx / 36;
            wlds[idx] = (oc < 3) ? wgt[((oc * 64) + ic0 + ic) * 9 + tap] * s64 : 0.f;
        }
        __syncthreads();
#pragma unroll 2
        for (int ic = 0; ic < 8; ++ic)
#pragma unroll
            for (int dy = 0; dy < 3; ++dy)
#pragma unroll
                for (int dx = 0; dx < 3; ++dx) {
                    float xv[4];
#pragma unroll
                    for (int k = 0; k < 4; ++k)
                        xv[k] = slds[ic][yb + 8 * k + dy][x + dx];
                    const float* wrow = &wlds[(ic * 9 + dy * 3 + dx) * 4];
#pragma unroll
                    for (int oc = 0; oc < 3; ++oc) {
                        float wv = wrow[oc];
#pragma unroll
                        for (int k = 0; k < 4; ++k) acc[oc][k] = fmaf(wv, xv[k], acc[oc][k]);
                    }
                }
        __syncthreads();
    }
#pragma unroll
    for (int oc = 0; oc < 3; ++oc) {
        float bv = bias[oc];
#pragma unroll
        for (int k = 0; k < 4; ++k) {
            int gy = tY + yb + 8 * k, gx = tX + x;
            out[(((size_t)b * 3 + oc) * H + gy) * W + gx] = acc[oc][k] + bv;
        }
    }
}

extern "C" void kernel_launch(void* const* d_in, const int* in_sizes, int n_in,
                              void* d_out, int out_size, void* d_ws, size_t ws_size,
                              hipStream_t stream) {
    const float* x     = (const float*)d_in[0];
    const float* cf    = (const float*)d_in[1];
    const float* in_w  = (const float*)d_in[2];
    const float* in_b  = (const float*)d_in[3];
    const float* blk_w = (const float*)d_in[4];
    const float* blk_b = (const float*)d_in[5];
    const float* mod_w = (const float*)d_in[6];
    const float* mod_b = (const float*)d_in[7];
    const float* up_w  = (const float*)d_in[8];
    const float* up_b  = (const float*)d_in[9];
    const float* out_w = (const float*)d_in[10];
    const float* out_b = (const float*)d_in[11];
    float* outp = (float*)d_out;

    u16 *bufA, *bufB, *bufC, *wblk, *wup;
    float *bufE, *modp;
    hipGetSymbolAddress((void**)&bufA, HIP_SYMBOL(g_bufA));
    hipGetSymbolAddress((void**)&bufB, HIP_SYMBOL(g_bufB));
    hipGetSymbolAddress((void**)&bufC, HIP_SYMBOL(g_bufC));
    hipGetSymbolAddress((void**)&bufE, HIP_SYMBOL(g_bufE));
    hipGetSymbolAddress((void**)&modp, HIP_SYMBOL(g_mod));
    hipGetSymbolAddress((void**)&wblk, HIP_SYMBOL(g_wblk));
    hipGetSymbolAddress((void**)&wup,  HIP_SYMBOL(g_wup));

    mod_kernel<<<dim3(20, 4), 64, 0, stream>>>(cf, mod_w, mod_b, modp);
    prep_blk_kernel<<<dim3(20, 4), 256, 0, stream>>>(blk_w, modp, wblk);
    prep_up_kernel<<<dim3(2, 4), 256, 0, stream>>>(up_w, wup);

    in_conv_kernel<<<dim3(4, 4, 16), 256, 0, stream>>>(x, in_w, in_b, bufA);

    for (int i = 0; i < 10; ++i) {
        mconv_kernel<true, false, 0><<<dim3(8, 16, 4), 256, 0, stream>>>(
            bufA, wblk + (size_t)(2 * i) * 4 * 73728, blk_b + (2 * i) * 64,
            nullptr, bufB, 128, 128, 1, 73728);
        mconv_kernel<false, true, 0><<<dim3(8, 16, 4), 256, 0, stream>>>(
            bufB, wblk + (size_t)(2 * i + 1) * 4 * 73728, blk_b + (2 * i + 1) * 64,
            bufA, bufA, 128, 128, 1, 73728);
    }

    // up0: 64->256 @128^2 -> shuffle -> bufC (256^2, bf16 hi/lo)
    mconv_kernel<false, false, 1><<<dim3(8, 16, 16), 256, 0, stream>>>(
        bufA, wup, up_b, nullptr, bufC, 128, 128, 4, 0);
    // up1: 64->256 @256^2 -> shuffle -> bufE (512^2, fp32 ch-last)
    mconv_kernel<false, false, 2><<<dim3(16, 32, 16), 256, 0, stream>>>(
        bufC, wup + (size_t)4 * 73728, up_b + 256, nullptr, bufE, 256, 256, 4, 0);

    out_conv_kernel<<<dim3(16, 16, 4), 256, 0, stream>>>(bufE, out_w, out_b, outp);
}

// Round 4
// 759.792 us; speedup vs baseline: 7.5055x; 1.6895x over previous
//
#include <hip/hip_runtime.h>
#include <math.h>

typedef unsigned short u16;
typedef unsigned int u32;
typedef float f32x4 __attribute__((ext_vector_type(4)));
typedef float f32x2 __attribute__((ext_vector_type(2)));
typedef _Float16 f16;
typedef f16 f16x8 __attribute__((ext_vector_type(8)));
typedef f16 f16x4 __attribute__((ext_vector_type(4)));
typedef u32 u32x4 __attribute__((ext_vector_type(4)));
typedef u16 u16x4 __attribute__((ext_vector_type(4)));

// ---------------------------------------------------------------------------
// fp16 2-term split: x*w = x*whi + (x*(wlo*256))*2^-8, dual f32 accumulators.
// Trunk (residual chain) kept fp32 in bufR; conv inputs rounded to fp16 once.
// Weights pre-split per (layer,batch) frag blobs, modulation folded in.
// mconv: A staged per-tap to LDS via global_load_lds (dbuf); B tile in LDS
// with balanced XOR swizzle; SHUF via LDS transpose -> planar fp16 out.
// ---------------------------------------------------------------------------

__device__ u16  g_bufB[(size_t)4*128*128*64];   // conv1 out, fp16 ch-last
__device__ float g_bufR[(size_t)4*128*128*64];  // trunk, fp32 ch-last
__device__ u16  g_bufC[(size_t)4*256*256*64];   // up0 out, fp16 planar [4][b][y][x][16]
__device__ u16  g_bufE[(size_t)4*512*512*64];   // up1 out, fp16 planar
__device__ float g_mod[20*4*64];
// frag blobs: [set][tap9][ck4][mt4][lane64][8]  (ck0,1=whi ic0-31/32-63; ck2,3=wlo*256)
__device__ f16 g_wblk[(size_t)20*4*73728];
__device__ f16 g_wup[(size_t)2*4*73728];
__device__ u16 g_zero[8];                       // never written: stays zero

__device__ __forceinline__ void gll16(const void* g, void* l) {
    __builtin_amdgcn_global_load_lds(
        (const __attribute__((address_space(1))) unsigned*)g,
        (__attribute__((address_space(3))) unsigned*)l, 16, 0, 0);
}

__global__ void mod_kernel(const float* __restrict__ cf,
                           const float* __restrict__ mw,
                           const float* __restrict__ mb,
                           float* __restrict__ mod) {
    int m = blockIdx.x, b = blockIdx.y, o = threadIdx.x;
    const float* wrow = mw + (m * 64 + o) * 128;
    const float* cfb  = cf + b * 128;
    float s = 0.f;
#pragma unroll 8
    for (int c = 0; c < 128; ++c) s = fmaf(cfb[c], wrow[c], s);
    mod[(m * 4 + b) * 64 + o] = s * 0.08838834764831845f + mb[m * 64 + o];
}

__device__ __forceinline__ void split_store(f16* wp, float val) {
    f16 hi = (f16)val;
    f16 lo = (f16)((val - (float)hi) * 256.0f);
    wp[0] = hi;      // caller picks hi/lo slot via pointer math; see below
    wp[1] = lo;
}

__global__ void prep_blk_kernel(const float* __restrict__ bw,
                                const float* __restrict__ mod,
                                f16* __restrict__ wp) {
    int ly = blockIdx.x, b = blockIdx.y;
    const float s64 = 1.0f / 24.0f;
    size_t base = (size_t)(ly * 4 + b) * 73728;
    for (int idx = threadIdx.x; idx < 73728; idx += 256) {
        int j = idx & 7, l = (idx >> 3) & 63, mt = (idx >> 9) & 3,
            ck = (idx >> 11) & 3, tap = idx >> 13;
        int m = mt * 16 + (l & 15);
        int ic = (ck & 1) * 32 + (l >> 4) * 8 + j;
        float val = bw[((size_t)(ly * 64 + m) * 64 + ic) * 9 + tap] * s64 *
                    mod[(ly * 4 + b) * 64 + ic];
        f16 hi = (f16)val;
        wp[base + idx] = (ck < 2) ? hi : (f16)((val - (float)hi) * 256.0f);
    }
}

__global__ void prep_up_kernel(const float* __restrict__ uw, f16* __restrict__ wp) {
    int st = blockIdx.x, ocg = blockIdx.y;
    const float s64 = 1.0f / 24.0f;
    size_t base = (size_t)(st * 4 + ocg) * 73728;
    for (int idx = threadIdx.x; idx < 73728; idx += 256) {
        int j = idx & 7, l = (idx >> 3) & 63, mt = (idx >> 9) & 3,
            ck = (idx >> 11) & 3, tap = idx >> 13;
        int o = ocg * 64 + mt * 16 + (l & 15);
        int ic = (ck & 1) * 32 + (l >> 4) * 8 + j;
        float val = uw[((size_t)(st * 256 + o) * 64 + ic) * 9 + tap] * s64;
        f16 hi = (f16)val;
        wp[base + idx] = (ck < 2) ? hi : (f16)((val - (float)hi) * 256.0f);
    }
}

// --- input conv (3->64, fp32 scalar), writes trunk bufR fp32 ch-last
__global__ __launch_bounds__(256) void in_conv_kernel(
    const float* __restrict__ in, const float* __restrict__ wgt,
    const float* __restrict__ bias, float* __restrict__ out) {
    __shared__ float slds[3][34][35];
    __shared__ float wlds[3 * 9 * 16];
    const int H = 128, W = 128;
    const int tid = threadIdx.x, x = tid & 31, yb = tid >> 5;
    const int b = blockIdx.z >> 2, ocb = (blockIdx.z & 3) * 16;
    const int tY = blockIdx.y * 32, tX = blockIdx.x * 32;
    const float s_in = 0.19245008972987526f;

    float acc[16][4];
#pragma unroll
    for (int oc = 0; oc < 16; ++oc)
#pragma unroll
        for (int k = 0; k < 4; ++k) acc[oc][k] = 0.f;

    for (int idx = tid; idx < 3 * 34 * 34; idx += 256) {
        int ic = idx / (34 * 34), p = idx % (34 * 34);
        int r = p / 34, c = p % 34;
        int gy = tY + r - 1, gx = tX + c - 1;
        float v = 0.f;
        if (gy >= 0 && gy < H && gx >= 0 && gx < W)
            v = in[((b * 3 + ic) * H + gy) * W + gx] * s_in;
        slds[ic][r][c] = v;
    }
    for (int idx = tid; idx < 3 * 9 * 16; idx += 256) {
        int oc = idx & 15, tap = (idx >> 4) % 9, ic = idx / 144;
        wlds[idx] = wgt[((ocb + oc) * 3 + ic) * 9 + tap];
    }
    __syncthreads();

#pragma unroll
    for (int ic = 0; ic < 3; ++ic)
#pragma unroll
        for (int dy = 0; dy < 3; ++dy)
#pragma unroll
            for (int dx = 0; dx < 3; ++dx) {
                float xv[4];
#pragma unroll
                for (int k = 0; k < 4; ++k)
                    xv[k] = slds[ic][yb + 8 * k + dy][x + dx];
                const float* wrow = &wlds[(ic * 9 + dy * 3 + dx) * 16];
#pragma unroll
                for (int oc = 0; oc < 16; ++oc) {
                    float wv = wrow[oc];
#pragma unroll
                    for (int k = 0; k < 4; ++k) acc[oc][k] = fmaf(wv, xv[k], acc[oc][k]);
                }
            }

#pragma unroll
    for (int oc = 0; oc < 16; ++oc) {
        int goc = ocb + oc;
        float bv = bias[goc];
#pragma unroll
        for (int k = 0; k < 4; ++k) {
            int gy = tY + yb + 8 * k, gx = tX + x;
            size_t pixG = ((size_t)b * H + gy) * W + gx;
            out[pixG * 64 + goc] = acc[oc][k] + bv;
        }
    }
}

// --- MFMA conv. 512 thr, 8 waves. Tile 32 col x 8 row, 64 oc per block.
// wave = (cg,rg,mg): 16 cols x 4 rows x 2 mt.
// A: per-tap frag set (16KB) global_load_lds -> LDS, double-buffered.
// B: fp16 tile 10x34 px x 128B, XOR-swizzled, staged once.
// INMODE: 0=fp32 ch-last (cvt at stage), 1=fp16 ch-last (gll), 2=fp16 planar (gll)
// OUTMODE: 0=fp16 ch-last +ReLU, 1=fp32 resid RMW, 2=pixelshuffle planar fp16
template <int INMODE, int OUTMODE>
__global__ __launch_bounds__(512, 2) void mconv_kernel(
    const void* __restrict__ inv, const f16* __restrict__ wp,
    const float* __restrict__ bias, float* __restrict__ residR,
    void* __restrict__ outv, int H, int W, int OCG, int wp_bstride,
    size_t in_plstride, size_t out_plstride)
{
    __shared__ __align__(16) char smem[44032 + 32768];
    f16* sB = (f16*)smem;                  // [344 px][64] halfs (8 chunk-slots x 8)
    f16* sA = (f16*)(smem + 44032);        // 2 x 16 frags x 512 halfs

    const int tid = threadIdx.x;
    const int lane = tid & 63, wv = tid >> 6;
    const int lcol = lane & 15, lk8 = lane >> 4;
    const int cg = wv & 1, rg = (wv >> 1) & 1, mg = wv >> 2;
    const int b = blockIdx.z / OCG, ocg = blockIdx.z % OCG;
    const int y0 = blockIdx.y * 8, x0 = blockIdx.x * 32;
    const f16* wpb = wp + (size_t)b * wp_bstride + (size_t)ocg * 73728;
    const int cb = cg * 16 + lcol;

    // ---- issue A-stage tap0 -> buf0 (2 frags per wave)
    {
        int f = wv * 2;
        gll16(wpb + (size_t)f * 512 + lane * 8, sA + f * 512 + lane * 8);
        gll16(wpb + (size_t)(f + 1) * 512 + lane * 8, sA + (f + 1) * 512 + lane * 8);
    }

    // ---- stage B tile (rows -1..8, cols -1..32), swizzle slot = chunk^(px&7)
    if (INMODE == 0) {
        const float* inf = (const float*)inv;
        for (int idx = tid; idx < 2720; idx += 512) {
            int px = idx >> 3, c = idx & 7;
            int slot = c ^ (px & 7);
            int r = px / 34, cc = px - r * 34;
            int gy = y0 + r - 1, gx = x0 + cc - 1;
            f16x8 hv = (f16x8)(f16)0.f;
            if (gy >= 0 && gy < H && gx >= 0 && gx < W) {
                const float* p = inf + ((((size_t)b * H + gy) * W + gx) * 64 + c * 8);
                f32x4 lo4 = *(const f32x4*)p;
                f32x4 hi4 = *(const f32x4*)(p + 4);
#pragma unroll
                for (int k = 0; k < 4; ++k) { hv[k] = (f16)lo4[k]; hv[4 + k] = (f16)hi4[k]; }
            }
            *(f16x8*)(sB + px * 64 + slot * 8) = hv;
        }
    } else {
        const f16* inh = (const f16*)inv;
        for (int i = wv; i < 43; i += 8) {
            int px = i * 8 + (lane >> 3);
            int slot = lane & 7;
            int c = slot ^ (px & 7);
            int r = px / 34, cc = px - r * 34;
            int gy = y0 + r - 1, gx = x0 + cc - 1;
            bool ok = (px < 340) && gy >= 0 && gy < H && gx >= 0 && gx < W;
            const void* src;
            if (INMODE == 1)
                src = inh + ((((size_t)b * H + gy) * W + gx) * 64 + c * 8);
            else
                src = inh + ((size_t)(c >> 1) * in_plstride +
                             (((size_t)b * H + gy) * W + gx) * 16 + (c & 1) * 8);
            if (!ok) src = g_zero;
            gll16(src, sB + i * 512 + lane * 8);
        }
    }
    __syncthreads();   // drains vmcnt: A tap0 + B all landed

    f32x4 ah[4][2], al[4][2];
#pragma unroll
    for (int r = 0; r < 4; ++r)
#pragma unroll
        for (int m = 0; m < 2; ++m) { ah[r][m] = (f32x4)0.f; al[r][m] = (f32x4)0.f; }

#pragma unroll
    for (int tap = 0; tap < 9; ++tap) {
        const int dy = tap / 3, dx = tap - dy * 3;
        if (tap < 8) {   // issue next-tap A stage before compute
            int f = wv * 2;
            const f16* src = wpb + (size_t)(tap + 1) * 16 * 512;
            f16* dst = sA + ((tap + 1) & 1) * 8192;
            gll16(src + (size_t)f * 512 + lane * 8, dst + f * 512 + lane * 8);
            gll16(src + (size_t)(f + 1) * 512 + lane * 8, dst + (f + 1) * 512 + lane * 8);
        }
        const f16* sAc = sA + (tap & 1) * 8192;
        f16x8 Af[2][4];
#pragma unroll
        for (int m = 0; m < 2; ++m)
#pragma unroll
            for (int ck = 0; ck < 4; ++ck)
                Af[m][ck] = *(const f16x8*)(sAc + (ck * 4 + mg * 2 + m) * 512 + lane * 8);

        const int prow = (rg * 4 + dy) * 34 + cb + dx;
#pragma unroll
        for (int r = 0; r < 4; ++r) {
            int px = prow + r * 34;
            int sw = px & 7;
            f16x8 B0 = *(const f16x8*)(sB + px * 64 + ((lk8 ^ sw) * 8));
            f16x8 B1 = *(const f16x8*)(sB + px * 64 + (((4 + lk8) ^ sw) * 8));
#pragma unroll
            for (int m = 0; m < 2; ++m) {
                ah[r][m] = __builtin_amdgcn_mfma_f32_16x16x32_f16(Af[m][0], B0, ah[r][m], 0, 0, 0);
                ah[r][m] = __builtin_amdgcn_mfma_f32_16x16x32_f16(Af[m][1], B1, ah[r][m], 0, 0, 0);
                al[r][m] = __builtin_amdgcn_mfma_f32_16x16x32_f16(Af[m][2], B0, al[r][m], 0, 0, 0);
                al[r][m] = __builtin_amdgcn_mfma_f32_16x16x32_f16(Af[m][3], B1, al[r][m], 0, 0, 0);
            }
        }
        __syncthreads();
    }

    // ---- epilogue. C/D frag: col(px)=lane&15, row(oc)=lk8*4+reg
    if (OUTMODE == 0) {
        f16* out = (f16*)outv;
#pragma unroll
        for (int r = 0; r < 4; ++r) {
            int gy = y0 + rg * 4 + r, gx = x0 + cb;
            size_t pixG = ((size_t)b * H + gy) * W + gx;
#pragma unroll
            for (int m = 0; m < 2; ++m) {
                int oc0 = (mg * 2 + m) * 16 + lk8 * 4;
                f32x4 v = ah[r][m] + al[r][m] * 0.00390625f;
                f32x4 bv = *(const f32x4*)(bias + oc0);
                v += bv;
                f16x4 o;
#pragma unroll
                for (int j = 0; j < 4; ++j) o[j] = (f16)fmaxf(v[j], 0.f);
                *(f16x4*)(out + pixG * 64 + oc0) = o;
            }
        }
    } else if (OUTMODE == 1) {
#pragma unroll
        for (int r = 0; r < 4; ++r) {
            int gy = y0 + rg * 4 + r, gx = x0 + cb;
            size_t pixG = ((size_t)b * H + gy) * W + gx;
#pragma unroll
            for (int m = 0; m < 2; ++m) {
                int oc0 = (mg * 2 + m) * 16 + lk8 * 4;
                f32x4 v = ah[r][m] + al[r][m] * 0.00390625f;
                f32x4 bv = *(const f32x4*)(bias + oc0);
                v += bv;
                float* rp = residR + pixG * 64 + oc0;
                f32x4 rv = *(const f32x4*)rp;
                v += rv;
                *(f32x4*)rp = v;
            }
        }
    } else {
        // pixel-shuffle: acc f32x4 j -> (oy=2y+(j>>1), ox=2x+(j&1)), ch cc
        f16* sT = sA;   // [16 ch][1024 opx] halfs = 32KB (sA free after barrier)
#pragma unroll
        for (int r = 0; r < 4; ++r) {
#pragma unroll
            for (int m = 0; m < 2; ++m) {
                int oc0 = (mg * 2 + m) * 16 + lk8 * 4;
                int cc = (mg * 2 + m) * 4 + lk8;
                f32x4 v = ah[r][m] + al[r][m] * 0.00390625f;
                f32x4 bv = *(const f32x4*)(bias + ocg * 64 + oc0);
                v += bv;
#pragma unroll
                for (int jp = 0; jp < 2; ++jp) {
                    int oy = 2 * (rg * 4 + r) + jp;
                    int opx = oy * 64 + 2 * cb;
                    f16 e0 = (f16)v[jp * 2], e1 = (f16)v[jp * 2 + 1];
                    u32 w = ((u32)*(u16*)&e0) | (((u32)*(u16*)&e1) << 16);
                    *(u32*)(sT + cc * 1024 + opx) = w;
                }
            }
        }
        __syncthreads();
        f16* out = (f16*)outv + (size_t)ocg * out_plstride;
        const int H2 = 2 * H, W2 = 2 * W;
        {
            int t = tid;
            u32 tv[16];
#pragma unroll
            for (int c = 0; c < 16; ++c) tv[c] = *(const u32*)(sT + c * 1024 + t * 2);
            int opx = t * 2;
            int oy = opx >> 6, ox = opx & 63;
            size_t gbase = (((size_t)b * H2 + 2 * y0 + oy) * W2 + 2 * x0 + ox) * 16;
            u16x4 q[8];
#pragma unroll
            for (int c = 0; c < 16; ++c) {
                ((u16*)q)[c] = (u16)(tv[c] & 0xffff);
                ((u16*)q)[16 + c] = (u16)(tv[c] >> 16);
            }
#pragma unroll
            for (int s = 0; s < 4; ++s) *(u16x4*)(out + gbase + s * 4) = q[s];
#pragma unroll
            for (int s = 0; s < 4; ++s) *(u16x4*)(out + gbase + 16 + s * 4) = q[4 + s];
        }
    }
}

// --- output conv (64->3, 512x512, fp32 scalar), fp16 planar input
__global__ __launch_bounds__(256) void out_conv_kernel(
    const u16* __restrict__ in, const float* __restrict__ wgt,
    const float* __restrict__ bias, float* __restrict__ out) {
    __shared__ float slds[8][34][35];
    __shared__ float wlds[8 * 9 * 4];
    const int H = 512, W = 512;
    const size_t PLE = (size_t)4 * 512 * 512 * 16;
    const int tid = threadIdx.x, x = tid & 31, yb = tid >> 5;
    const int b = blockIdx.z;
    const int tY = blockIdx.y * 32, tX = blockIdx.x * 32;
    const float s64 = 1.0f / 24.0f;

    float acc[3][4];
#pragma unroll
    for (int oc = 0; oc < 3; ++oc)
#pragma unroll
        for (int k = 0; k < 4; ++k) acc[oc][k] = 0.f;

    for (int ic0 = 0; ic0 < 64; ic0 += 8) {
        for (int idx = tid; idx < 34 * 34 * 8; idx += 256) {
            int ic = idx & 7, pix = idx >> 3;
            int r = pix / 34, c = pix - r * 34;
            int gy = tY + r - 1, gx = tX + c - 1;
            float v = 0.f;
            if (gy >= 0 && gy < H && gx >= 0 && gx < W) {
                int gic = ic0 + ic;
                const f16* ph = (const f16*)(in) + (size_t)(gic >> 4) * PLE +
                                (((size_t)b * H + gy) * W + gx) * 16 + (gic & 15);
                v = (float)*ph;
            }
            slds[ic][r][c] = v;
        }
        for (int idx = tid; idx < 8 * 9 * 4; idx += 256) {
            int oc = idx & 3, tap = (idx >> 2) % 9, ic = idx / 36;
            wlds[idx] = (oc < 3) ? wgt[((oc * 64) + ic0 + ic) * 9 + tap] * s64 : 0.f;
        }
        __syncthreads();
#pragma unroll 2
        for (int ic = 0; ic < 8; ++ic)
#pragma unroll
            for (int dy = 0; dy < 3; ++dy)
#pragma unroll
                for (int dx = 0; dx < 3; ++dx) {
                    float xv[4];
#pragma unroll
                    for (int k = 0; k < 4; ++k)
                        xv[k] = slds[ic][yb + 8 * k + dy][x + dx];
                    const float* wrow = &wlds[(ic * 9 + dy * 3 + dx) * 4];
#pragma unroll
                    for (int oc = 0; oc < 3; ++oc) {
                        float wv = wrow[oc];
#pragma unroll
                        for (int k = 0; k < 4; ++k) acc[oc][k] = fmaf(wv, xv[k], acc[oc][k]);
                    }
                }
        __syncthreads();
    }
#pragma unroll
    for (int oc = 0; oc < 3; ++oc) {
        float bv = bias[oc];
#pragma unroll
        for (int k = 0; k < 4; ++k) {
            int gy = tY + yb + 8 * k, gx = tX + x;
            out[(((size_t)b * 3 + oc) * H + gy) * W + gx] = acc[oc][k] + bv;
        }
    }
}

extern "C" void kernel_launch(void* const* d_in, const int* in_sizes, int n_in,
                              void* d_out, int out_size, void* d_ws, size_t ws_size,
                              hipStream_t stream) {
    const float* x     = (const float*)d_in[0];
    const float* cf    = (const float*)d_in[1];
    const float* in_w  = (const float*)d_in[2];
    const float* in_b  = (const float*)d_in[3];
    const float* blk_w = (const float*)d_in[4];
    const float* blk_b = (const float*)d_in[5];
    const float* mod_w = (const float*)d_in[6];
    const float* mod_b = (const float*)d_in[7];
    const float* up_w  = (const float*)d_in[8];
    const float* up_b  = (const float*)d_in[9];
    const float* out_w = (const float*)d_in[10];
    const float* out_b = (const float*)d_in[11];
    float* outp = (float*)d_out;

    u16 *bufB, *bufC, *bufE;
    float *bufR, *modp;
    f16 *wblk, *wup;
    hipGetSymbolAddress((void**)&bufB, HIP_SYMBOL(g_bufB));
    hipGetSymbolAddress((void**)&bufR, HIP_SYMBOL(g_bufR));
    hipGetSymbolAddress((void**)&bufC, HIP_SYMBOL(g_bufC));
    hipGetSymbolAddress((void**)&bufE, HIP_SYMBOL(g_bufE));
    hipGetSymbolAddress((void**)&modp, HIP_SYMBOL(g_mod));
    hipGetSymbolAddress((void**)&wblk, HIP_SYMBOL(g_wblk));
    hipGetSymbolAddress((void**)&wup,  HIP_SYMBOL(g_wup));

    mod_kernel<<<dim3(20, 4), 64, 0, stream>>>(cf, mod_w, mod_b, modp);
    prep_blk_kernel<<<dim3(20, 4), 256, 0, stream>>>(blk_w, modp, wblk);
    prep_up_kernel<<<dim3(2, 4), 256, 0, stream>>>(up_w, wup);

    // input conv -> trunk fp32
    in_conv_kernel<<<dim3(4, 4, 16), 256, 0, stream>>>(x, in_w, in_b, bufR);

    const size_t PLC = (size_t)4 * 256 * 256 * 16;
    const size_t PLEp = (size_t)4 * 512 * 512 * 16;

    for (int i = 0; i < 10; ++i) {
        // conv1: bufR(f32) -> bufB(f16), ReLU
        mconv_kernel<0, 0><<<dim3(4, 16, 4), 512, 0, stream>>>(
            bufR, wblk + (size_t)(2 * i) * 4 * 73728, blk_b + (2 * i) * 64,
            nullptr, bufB, 128, 128, 1, 73728, 0, 0);
        // conv2: bufB(f16) -> bufR += (residual RMW, fp32)
        mconv_kernel<1, 1><<<dim3(4, 16, 4), 512, 0, stream>>>(
            bufB, wblk + (size_t)(2 * i + 1) * 4 * 73728, blk_b + (2 * i + 1) * 64,
            bufR, nullptr, 128, 128, 1, 73728, 0, 0);
    }

    // up0: bufR(f32) @128^2 -> shuffle -> bufC (fp16 planar, 256^2)
    mconv_kernel<0, 2><<<dim3(4, 16, 16), 512, 0, stream>>>(
        bufR, wup, up_b, nullptr, bufC, 128, 128, 4, 0, 0, PLC);
    // up1: bufC(f16 planar) @256^2 -> shuffle -> bufE (fp16 planar, 512^2)
    mconv_kernel<2, 2><<<dim3(8, 32, 16), 512, 0, stream>>>(
        bufC, wup + (size_t)4 * 73728, up_b + 256, nullptr, bufE, 256, 256, 4,
        0, PLC, PLEp);

    out_conv_kernel<<<dim3(16, 16, 4), 256, 0, stream>>>(bufE, out_w, out_b, outp);
}

// Round 5
// 540.579 us; speedup vs baseline: 10.5491x; 1.4055x over previous
//
#include <hip/hip_runtime.h>
#include <math.h>

typedef unsigned short u16;
typedef unsigned int u32;
typedef float f32x4 __attribute__((ext_vector_type(4)));
typedef _Float16 f16;
typedef f16 f16x8 __attribute__((ext_vector_type(8)));
typedef f16 f16x4 __attribute__((ext_vector_type(4)));
typedef u32 u32x4 __attribute__((ext_vector_type(4)));

// ---------------------------------------------------------------------------
// Single-term fp16 conv GEMM: x*w with fp16 weights (mod folded), fp32 accum.
// Trunk kept fp32 (bufR) + fp16 mirror (bufT). K=64 split as 2 kf passes of
// 32 ic; LDS B-tile stored plane-major [k8][row][col] in 16B granules ->
// conflict-free ds_read_b128 and gll16-stageable. A staged per (kf,dx) via
// global_load_lds, double-buffered. dy-row-sharing: each B row feeds 3 dy.
// ---------------------------------------------------------------------------

__device__ u16  g_bufT[(size_t)4*128*128*64];    // trunk fp16 ch-last
__device__ float g_bufR[(size_t)4*128*128*64];   // trunk fp32 ch-last
__device__ u16  g_bufB[(size_t)4*128*128*64];    // conv1 out fp16 ch-last
__device__ u16  g_bufC[(size_t)4*4*256*256*16];  // up0 out fp16 planar16
__device__ u16  g_bufE[(size_t)4*4*512*512*16];  // up1 out fp16 planar16
__device__ float g_mod[20*4*64];
// frag blobs: [set][tap9][kf2][mt][lane64][8]
__device__ f16 g_wblk[(size_t)20*4*36864];
__device__ f16 g_wup[(size_t)2*4*36864];
__device__ f16 g_wout[9216];
__device__ u16 g_zero[8];                        // stays zero

__device__ __forceinline__ void gll16(const void* g, void* l) {
    __builtin_amdgcn_global_load_lds(
        (const __attribute__((address_space(1))) unsigned*)g,
        (__attribute__((address_space(3))) unsigned*)l, 16, 0, 0);
}

__global__ void mod_kernel(const float* __restrict__ cf,
                           const float* __restrict__ mw,
                           const float* __restrict__ mb,
                           float* __restrict__ mod) {
    int m = blockIdx.x, b = blockIdx.y, o = threadIdx.x;
    const float* wrow = mw + (m * 64 + o) * 128;
    const float* cfb  = cf + b * 128;
    float s = 0.f;
#pragma unroll 8
    for (int c = 0; c < 128; ++c) s = fmaf(cfb[c], wrow[c], s);
    mod[(m * 4 + b) * 64 + o] = s * 0.08838834764831845f + mb[m * 64 + o];
}

__global__ void prep_blk_kernel(const float* __restrict__ bw,
                                const float* __restrict__ mod,
                                f16* __restrict__ wp) {
    int c = blockIdx.x, b = blockIdx.y;
    const float s64 = 1.0f / 24.0f;
    size_t base = (size_t)(c * 4 + b) * 36864;
    for (int idx = threadIdx.x; idx < 36864; idx += 256) {
        int j = idx & 7, l = (idx >> 3) & 63;
        int frag = idx >> 9;               // [0,72)
        int mt = frag & 3, kfr = frag >> 2;
        int kf = kfr & 1, tap = kfr >> 1;
        int oc = mt * 16 + (l & 15);
        int ic = kf * 32 + (l >> 4) * 8 + j;
        float val = bw[((size_t)(c * 64 + oc) * 64 + ic) * 9 + tap] * s64 *
                    mod[(c * 4 + b) * 64 + ic];
        wp[base + idx] = (f16)val;
    }
}

__global__ void prep_up_kernel(const float* __restrict__ uw, f16* __restrict__ wp) {
    int st = blockIdx.x, ocg = blockIdx.y;
    const float s64 = 1.0f / 24.0f;
    size_t base = (size_t)(st * 4 + ocg) * 36864;
    for (int idx = threadIdx.x; idx < 36864; idx += 256) {
        int j = idx & 7, l = (idx >> 3) & 63;
        int frag = idx >> 9;
        int mt = frag & 3, kfr = frag >> 2;
        int kf = kfr & 1, tap = kfr >> 1;
        int oc = ocg * 64 + mt * 16 + (l & 15);
        int ic = kf * 32 + (l >> 4) * 8 + j;
        wp[base + idx] = (f16)(uw[((size_t)(st * 256 + oc) * 64 + ic) * 9 + tap] * s64);
    }
}

__global__ void prep_out_kernel(const float* __restrict__ ow, f16* __restrict__ wp) {
    const float s64 = 1.0f / 24.0f;
    for (int idx = threadIdx.x; idx < 9216; idx += 256) {
        int j = idx & 7, l = (idx >> 3) & 63;
        int frag = idx >> 9;               // [0,18): kf + tap*2
        int kf = frag & 1, tap = frag >> 1;
        int oc = l & 15;
        int ic = kf * 32 + (l >> 4) * 8 + j;
        float val = (oc < 3) ? ow[((size_t)(oc * 64) + ic) * 9 + tap] * s64 : 0.f;
        wp[idx] = (f16)val;
    }
}

// --- input conv (3->64, fp32 scalar), writes bufR fp32 + bufT fp16 (ch-last)
__global__ __launch_bounds__(256) void in_conv_kernel(
    const float* __restrict__ in, const float* __restrict__ wgt,
    const float* __restrict__ bias, float* __restrict__ outR,
    u16* __restrict__ outT) {
    __shared__ float slds[3][34][35];
    __shared__ float wlds[3 * 9 * 16];
    const int H = 128, W = 128;
    const int tid = threadIdx.x, x = tid & 31, yb = tid >> 5;
    const int b = blockIdx.z >> 2, ocb = (blockIdx.z & 3) * 16;
    const int tY = blockIdx.y * 32, tX = blockIdx.x * 32;
    const float s_in = 0.19245008972987526f;

    float acc[16][4];
#pragma unroll
    for (int oc = 0; oc < 16; ++oc)
#pragma unroll
        for (int k = 0; k < 4; ++k) acc[oc][k] = 0.f;

    for (int idx = tid; idx < 3 * 34 * 34; idx += 256) {
        int ic = idx / (34 * 34), p = idx % (34 * 34);
        int r = p / 34, c = p % 34;
        int gy = tY + r - 1, gx = tX + c - 1;
        float v = 0.f;
        if (gy >= 0 && gy < H && gx >= 0 && gx < W)
            v = in[((b * 3 + ic) * H + gy) * W + gx] * s_in;
        slds[ic][r][c] = v;
    }
    for (int idx = tid; idx < 3 * 9 * 16; idx += 256) {
        int oc = idx & 15, tap = (idx >> 4) % 9, ic = idx / 144;
        wlds[idx] = wgt[((ocb + oc) * 3 + ic) * 9 + tap];
    }
    __syncthreads();

#pragma unroll
    for (int ic = 0; ic < 3; ++ic)
#pragma unroll
        for (int dy = 0; dy < 3; ++dy)
#pragma unroll
            for (int dx = 0; dx < 3; ++dx) {
                float xv[4];
#pragma unroll
                for (int k = 0; k < 4; ++k)
                    xv[k] = slds[ic][yb + 8 * k + dy][x + dx];
                const float* wrow = &wlds[(ic * 9 + dy * 3 + dx) * 16];
#pragma unroll
                for (int oc = 0; oc < 16; ++oc) {
                    float wv = wrow[oc];
#pragma unroll
                    for (int k = 0; k < 4; ++k) acc[oc][k] = fmaf(wv, xv[k], acc[oc][k]);
                }
            }

#pragma unroll
    for (int oc = 0; oc < 16; ++oc) {
        int goc = ocb + oc;
        float bv = bias[goc];
#pragma unroll
        for (int k = 0; k < 4; ++k) {
            int gy = tY + yb + 8 * k, gx = tX + x;
            size_t pixG = ((size_t)b * H + gy) * W + gx;
            float v = acc[oc][k] + bv;
            outR[pixG * 64 + goc] = v;
            outT[pixG * 64 + goc] = __builtin_bit_cast(u16, (f16)v);
        }
    }
}

// --- unified MFMA conv template
// wave = 16 cols x ROWS rows x (MT/MG)*16 oc.  4 waves: cg/rg/mg split.
// INMODE: 1 = fp16 ch-last[64], 2 = fp16 planar16
// OUTMODE: 0 = fp16 ch-last + ReLU, 1 = fp32 trunk RMW + fp16 mirror,
//          2 = pixel-shuffle -> planar16 fp16, 3 = fp32 NCHW (oc<3)
template <int CG, int RG, int MG, int MT, int ROWS, int INMODE, int OUTMODE, int LB>
__global__ __launch_bounds__(256, LB) void mconv(
    const u16* __restrict__ inh, const f16* __restrict__ wp,
    const float* __restrict__ bias, float* __restrict__ rbuf,
    void* __restrict__ outv, u16* __restrict__ outT,
    int H, int W, int OCG, int wp_bstride, size_t in_pl, size_t out_pl)
{
    constexpr int TC = CG * 16, TR = RG * ROWS;
    constexpr int CST = TC + 2, RST = TR + 2;
    constexpr int PXT = RST * CST;
    constexpr int PXP = (PXT + 63) & ~63;
    constexpr int MT_W = MT / MG;
    constexpr int NW = CG * RG * MG;      // 4 waves
    constexpr int SB_H = 4 * PXP * 8;     // halfs
    constexpr int SA_H = 2 * 3 * MT * 512;

    __shared__ __align__(16) u16 smem[SB_H + SA_H];
    u16* sB = smem;
    u16* sA = smem + SB_H;

    const int tid = threadIdx.x;
    const int lane = tid & 63, wv = tid >> 6;
    const int lcol = lane & 15, lk8 = lane >> 4;
    const int cg = (CG > 1) ? (wv % CG) : 0;
    const int rg = (wv / CG) % RG;
    const int mg = wv / (CG * RG);
    const int b = blockIdx.z / OCG, ocg = blockIdx.z % OCG;
    const int y0 = blockIdx.y * TR, x0 = blockIdx.x * TC;
    const f16* wpb = wp + (size_t)b * wp_bstride + (size_t)ocg * 36864;

    auto stageA = [&](int kf, int dx, int buf) {
        for (int f = wv; f < 3 * MT; f += NW) {
            int dy = f / MT, mt = f - dy * MT;
            const f16* src = wpb + ((size_t)((dy * 3 + dx) * 2 + kf) * MT + mt) * 512 + lane * 8;
            gll16(src, sA + ((size_t)(buf * 3 * MT + f)) * 512 + lane * 8);
        }
    };
    auto stageB = [&](int kf) {
        for (int g0 = wv * 64; g0 < 4 * PXP; g0 += NW * 64) {
            int g = g0 + lane;
            int pl = g / PXP, px = g - pl * PXP;
            int t = px / CST, c = px - t * CST;
            int gy = y0 + t - 1, gx = x0 + c - 1;
            const void* src = g_zero;
            if (px < PXT && gy >= 0 && gy < H && gx >= 0 && gx < W) {
                size_t pix = ((size_t)b * H + gy) * W + gx;
                int ic = kf * 32 + pl * 8;
                if (INMODE == 1)
                    src = inh + pix * 64 + ic;
                else
                    src = inh + (size_t)(ic >> 4) * in_pl + pix * 16 + (ic & 15);
            }
            gll16(src, sB + (size_t)g * 8);
        }
    };

    f32x4 acc[ROWS][MT_W];
#pragma unroll
    for (int r = 0; r < ROWS; ++r)
#pragma unroll
        for (int m = 0; m < MT_W; ++m) acc[r][m] = (f32x4)0.f;

    stageB(0);
    stageA(0, 0, 0);
    __syncthreads();

    for (int s = 0; s < 6; ++s) {
        int kf = s / 3, dx = s - kf * 3;
        if (s == 3) {             // channel-half boundary: restage B
            stageB(1);
            __syncthreads();
        }
        if (s < 5) {
            int ns = s + 1;
            stageA(ns / 3, ns % 3, ns & 1);
        }
        // load A frags for this step
        f16x8 Af[3][MT_W];
        const int abase = (s & 1) * 3 * MT;
#pragma unroll
        for (int dy = 0; dy < 3; ++dy)
#pragma unroll
            for (int m = 0; m < MT_W; ++m)
                Af[dy][m] = *(const f16x8*)(sA + (size_t)(abase + dy * MT + mg * MT_W + m) * 512 + lane * 8);

        const u16* bbase = sB + (size_t)lk8 * PXP * 8;
        const int pcol = cg * 16 + dx + lcol;
#pragma unroll
        for (int iy = 0; iy < ROWS + 2; ++iy) {
            int px = (rg * ROWS + iy) * CST + pcol;
            f16x8 Bf = *(const f16x8*)(bbase + (size_t)px * 8);
#pragma unroll
            for (int dy = 0; dy < 3; ++dy) {
                constexpr int unused = 0; (void)unused;
                int r = iy - dy;
                if (r >= 0 && r < ROWS) {
#pragma unroll
                    for (int m = 0; m < MT_W; ++m)
                        acc[r][m] = __builtin_amdgcn_mfma_f32_16x16x32_f16(
                            Af[dy][m], Bf, acc[r][m], 0, 0, 0);
                }
            }
        }
        __syncthreads();
    }

    // ---- epilogue. C/D: col(px)=lane&15, row(oc)=lk8*4+reg
    if (OUTMODE == 0 || OUTMODE == 1) {
        u16* outh = (u16*)outv;
#pragma unroll
        for (int r = 0; r < ROWS; ++r) {
            int gy = y0 + rg * ROWS + r, gx = x0 + cg * 16 + lcol;
            size_t pixG = ((size_t)b * H + gy) * W + gx;
#pragma unroll
            for (int m = 0; m < MT_W; ++m) {
                int oc0 = (mg * MT_W + m) * 16 + lk8 * 4;
                f32x4 v = acc[r][m] + *(const f32x4*)(bias + oc0);
                if (OUTMODE == 0) {
                    f16x4 o;
#pragma unroll
                    for (int j = 0; j < 4; ++j) o[j] = (f16)fmaxf(v[j], 0.f);
                    *(f16x4*)(outh + pixG * 64 + oc0) = o;
                } else {
                    float* rp = rbuf + pixG * 64 + oc0;
                    f32x4 rv = *(const f32x4*)rp;
                    v += rv;
                    *(f32x4*)rp = v;
                    f16x4 o;
#pragma unroll
                    for (int j = 0; j < 4; ++j) o[j] = (f16)v[j];
                    *(f16x4*)(outT + pixG * 64 + oc0) = o;
                }
            }
        }
    } else if (OUTMODE == 2) {
        // pixel shuffle via LDS transpose: sT[16 cc][NP pairs] u32
        constexpr int NP = 2 * TR * TC;   // x-pairs * out-rows
        __syncthreads();
        u32* sT = (u32*)smem;
#pragma unroll
        for (int r = 0; r < ROWS; ++r) {
#pragma unroll
            for (int m = 0; m < MT_W; ++m) {
                int oc0 = m * 16 + lk8 * 4;
                int cc = m * 4 + lk8;
                f32x4 v = acc[r][m] + *(const f32x4*)(bias + ocg * 64 + oc0);
                int oy = 2 * (rg * ROWS + r);
#pragma unroll
                for (int jp = 0; jp < 2; ++jp) {
                    f16 e0 = (f16)v[jp * 2], e1 = (f16)v[jp * 2 + 1];
                    u32 w = (u32)__builtin_bit_cast(u16, e0) |
                            ((u32)__builtin_bit_cast(u16, e1) << 16);
                    sT[cc * NP + (oy + jp) * TC + cg * 16 + lcol] = w;
                }
            }
        }
        __syncthreads();
        u16* outh = (u16*)outv + (size_t)ocg * out_pl;
        const int H2 = 2 * H, W2 = 2 * W;
#pragma unroll
        for (int it = 0; it < NP / 256; ++it) {
            int p = tid + it * 256;
            int oy = p / TC, xp = p - oy * TC;
            u32 tv[16];
#pragma unroll
            for (int c = 0; c < 16; ++c) tv[c] = sT[c * NP + p];
            u32 q0[8], q1[8];
#pragma unroll
            for (int c2 = 0; c2 < 8; ++c2) {
                q0[c2] = (tv[2 * c2] & 0xffffu) | (tv[2 * c2 + 1] << 16);
                q1[c2] = (tv[2 * c2] >> 16) | (tv[2 * c2 + 1] & 0xffff0000u);
            }
            int gy2 = 2 * y0 + oy, gx2 = 2 * x0 + 2 * xp;
            u16* dst = outh + (((size_t)b * H2 + gy2) * W2 + gx2) * 16;
            *(u32x4*)(dst)      = *(u32x4*)(q0);
            *(u32x4*)(dst + 8)  = *(u32x4*)(q0 + 4);
            *(u32x4*)(dst + 16) = *(u32x4*)(q1);
            *(u32x4*)(dst + 24) = *(u32x4*)(q1 + 4);
        }
    } else {
        // OUTMODE 3: fp32 NCHW, oc<3
        float* outp = (float*)outv;
        if (lk8 == 0) {
#pragma unroll
            for (int r = 0; r < ROWS; ++r) {
                int gy = y0 + rg * ROWS + r, gx = x0 + cg * 16 + lcol;
#pragma unroll
                for (int j = 0; j < 3; ++j) {
                    float v = acc[r][0][j] + bias[j];
                    outp[(((size_t)b * 3 + j) * H + gy) * W + gx] = v;
                }
            }
        }
    }
}

extern "C" void kernel_launch(void* const* d_in, const int* in_sizes, int n_in,
                              void* d_out, int out_size, void* d_ws, size_t ws_size,
                              hipStream_t stream) {
    const float* x     = (const float*)d_in[0];
    const float* cf    = (const float*)d_in[1];
    const float* in_w  = (const float*)d_in[2];
    const float* in_b  = (const float*)d_in[3];
    const float* blk_w = (const float*)d_in[4];
    const float* blk_b = (const float*)d_in[5];
    const float* mod_w = (const float*)d_in[6];
    const float* mod_b = (const float*)d_in[7];
    const float* up_w  = (const float*)d_in[8];
    const float* up_b  = (const float*)d_in[9];
    const float* out_w = (const float*)d_in[10];
    const float* out_b = (const float*)d_in[11];
    float* outp = (float*)d_out;

    u16 *bufT, *bufB, *bufC, *bufE;
    float *bufR, *modp;
    f16 *wblk, *wup, *wout;
    hipGetSymbolAddress((void**)&bufT, HIP_SYMBOL(g_bufT));
    hipGetSymbolAddress((void**)&bufR, HIP_SYMBOL(g_bufR));
    hipGetSymbolAddress((void**)&bufB, HIP_SYMBOL(g_bufB));
    hipGetSymbolAddress((void**)&bufC, HIP_SYMBOL(g_bufC));
    hipGetSymbolAddress((void**)&bufE, HIP_SYMBOL(g_bufE));
    hipGetSymbolAddress((void**)&modp, HIP_SYMBOL(g_mod));
    hipGetSymbolAddress((void**)&wblk, HIP_SYMBOL(g_wblk));
    hipGetSymbolAddress((void**)&wup,  HIP_SYMBOL(g_wup));
    hipGetSymbolAddress((void**)&wout, HIP_SYMBOL(g_wout));

    mod_kernel<<<dim3(20, 4), 64, 0, stream>>>(cf, mod_w, mod_b, modp);
    prep_blk_kernel<<<dim3(20, 4), 256, 0, stream>>>(blk_w, modp, wblk);
    prep_up_kernel<<<dim3(2, 4), 256, 0, stream>>>(up_w, wup);
    prep_out_kernel<<<1, 256, 0, stream>>>(out_w, wout);

    in_conv_kernel<<<dim3(4, 4, 16), 256, 0, stream>>>(x, in_w, in_b, bufR, bufT);

    const size_t PLC = (size_t)4 * 256 * 256 * 16;
    const size_t PLE = (size_t)4 * 512 * 512 * 16;

    for (int i = 0; i < 10; ++i) {
        // conv1: bufT -> bufB (fp16, ReLU)
        mconv<1, 2, 2, 4, 4, 1, 0, 2><<<dim3(8, 16, 4), 256, 0, stream>>>(
            bufT, wblk + (size_t)(2 * i) * 4 * 36864, blk_b + (2 * i) * 64,
            nullptr, bufB, nullptr, 128, 128, 1, 36864, 0, 0);
        // conv2: bufB -> trunk RMW (bufR fp32) + bufT mirror
        mconv<1, 2, 2, 4, 4, 1, 1, 2><<<dim3(8, 16, 4), 256, 0, stream>>>(
            bufB, wblk + (size_t)(2 * i + 1) * 4 * 36864, blk_b + (2 * i + 1) * 64,
            bufR, nullptr, bufT, 128, 128, 1, 36864, 0, 0);
    }

    // up0: bufT @128^2 -> shuffle -> bufC (planar16, 256^2)
    mconv<2, 2, 1, 4, 8, 1, 2, 2><<<dim3(4, 8, 16), 256, 0, stream>>>(
        bufT, wup, up_b, nullptr, bufC, nullptr, 128, 128, 4, 0, 0, PLC);
    // up1: bufC @256^2 -> shuffle -> bufE (planar16, 512^2)
    mconv<2, 2, 1, 4, 8, 2, 2, 2><<<dim3(8, 16, 16), 256, 0, stream>>>(
        bufC, wup + (size_t)4 * 36864, up_b + 256, nullptr, bufE, nullptr,
        256, 256, 4, 0, PLC, PLE);
    // out: bufE @512^2 -> fp32 NCHW (3 ch)
    mconv<2, 2, 1, 1, 8, 2, 3, 3><<<dim3(16, 32, 4), 256, 0, stream>>>(
        bufE, wout, out_b, nullptr, outp, nullptr, 512, 512, 1, 0, PLE, 0);
}

// Round 6
// 540.009 us; speedup vs baseline: 10.5603x; 1.0011x over previous
//
#include <hip/hip_runtime.h>
#include <math.h>

typedef unsigned short u16;
typedef unsigned int u32;
typedef float f32x4 __attribute__((ext_vector_type(4)));
typedef _Float16 f16;
typedef f16 f16x8 __attribute__((ext_vector_type(8)));
typedef f16 f16x4 __attribute__((ext_vector_type(4)));
typedef u32 u32x4 __attribute__((ext_vector_type(4)));

// ---------------------------------------------------------------------------
// Single-term fp16 conv GEMM: x*w with fp16 weights (mod folded), fp32 accum.
// Trunk kept fp32 (bufR) + fp16 mirror (bufT). K=64 split as 2 kf passes of
// 32 ic; LDS B-tile stored plane-major [k8][row][col] in 16B granules ->
// conflict-free ds_read_b128 and gll16-stageable. A staged per (kf,dx) via
// global_load_lds, double-buffered. dy-row-sharing: each B row feeds 3 dy.
// ---------------------------------------------------------------------------

__device__ u16  g_bufT[(size_t)4*128*128*64];    // trunk fp16 ch-last
__device__ float g_bufR[(size_t)4*128*128*64];   // trunk fp32 ch-last
__device__ u16  g_bufB[(size_t)4*128*128*64];    // conv1 out fp16 ch-last
__device__ u16  g_bufC[(size_t)4*4*256*256*16];  // up0 out fp16 planar16
__device__ u16  g_bufE[(size_t)4*4*512*512*16];  // up1 out fp16 planar16
__device__ float g_mod[20*4*64];
// frag blobs: [set][tap9][kf2][mt][lane64][8]
__device__ f16 g_wblk[(size_t)20*4*36864];
__device__ f16 g_wup[(size_t)2*4*36864];
__device__ f16 g_wout[9216];
__device__ u16 g_zero[8];                        // stays zero

__device__ __forceinline__ void gll16(const void* g, void* l) {
    __builtin_amdgcn_global_load_lds(
        (const __attribute__((address_space(1))) unsigned*)g,
        (__attribute__((address_space(3))) unsigned*)l, 16, 0, 0);
}

__global__ void mod_kernel(const float* __restrict__ cf,
                           const float* __restrict__ mw,
                           const float* __restrict__ mb,
                           float* __restrict__ mod) {
    int m = blockIdx.x, b = blockIdx.y, o = threadIdx.x;
    const float* wrow = mw + (m * 64 + o) * 128;
    const float* cfb  = cf + b * 128;
    float s = 0.f;
#pragma unroll 8
    for (int c = 0; c < 128; ++c) s = fmaf(cfb[c], wrow[c], s);
    mod[(m * 4 + b) * 64 + o] = s * 0.08838834764831845f + mb[m * 64 + o];
}

__global__ void prep_blk_kernel(const float* __restrict__ bw,
                                const float* __restrict__ mod,
                                f16* __restrict__ wp) {
    int c = blockIdx.x, b = blockIdx.y;
    const float s64 = 1.0f / 24.0f;
    size_t base = (size_t)(c * 4 + b) * 36864;
    for (int idx = threadIdx.x; idx < 36864; idx += 256) {
        int j = idx & 7, l = (idx >> 3) & 63;
        int frag = idx >> 9;               // [0,72)
        int mt = frag & 3, kfr = frag >> 2;
        int kf = kfr & 1, tap = kfr >> 1;
        int oc = mt * 16 + (l & 15);
        int ic = kf * 32 + (l >> 4) * 8 + j;
        float val = bw[((size_t)(c * 64 + oc) * 64 + ic) * 9 + tap] * s64 *
                    mod[(c * 4 + b) * 64 + ic];
        wp[base + idx] = (f16)val;
    }
}

__global__ void prep_up_kernel(const float* __restrict__ uw, f16* __restrict__ wp) {
    int st = blockIdx.x, ocg = blockIdx.y;
    const float s64 = 1.0f / 24.0f;
    size_t base = (size_t)(st * 4 + ocg) * 36864;
    for (int idx = threadIdx.x; idx < 36864; idx += 256) {
        int j = idx & 7, l = (idx >> 3) & 63;
        int frag = idx >> 9;
        int mt = frag & 3, kfr = frag >> 2;
        int kf = kfr & 1, tap = kfr >> 1;
        int oc = ocg * 64 + mt * 16 + (l & 15);
        int ic = kf * 32 + (l >> 4) * 8 + j;
        wp[base + idx] = (f16)(uw[((size_t)(st * 256 + oc) * 64 + ic) * 9 + tap] * s64);
    }
}

__global__ void prep_out_kernel(const float* __restrict__ ow, f16* __restrict__ wp) {
    const float s64 = 1.0f / 24.0f;
    for (int idx = threadIdx.x; idx < 9216; idx += 256) {
        int j = idx & 7, l = (idx >> 3) & 63;
        int frag = idx >> 9;               // [0,18): kf + tap*2
        int kf = frag & 1, tap = frag >> 1;
        int oc = l & 15;
        int ic = kf * 32 + (l >> 4) * 8 + j;
        float val = (oc < 3) ? ow[((size_t)(oc * 64) + ic) * 9 + tap] * s64 : 0.f;
        wp[idx] = (f16)val;
    }
}

// --- input conv (3->64, fp32 scalar), writes bufR fp32 + bufT fp16 (ch-last)
__global__ __launch_bounds__(256) void in_conv_kernel(
    const float* __restrict__ in, const float* __restrict__ wgt,
    const float* __restrict__ bias, float* __restrict__ outR,
    u16* __restrict__ outT) {
    __shared__ float slds[3][34][35];
    __shared__ float wlds[3 * 9 * 16];
    const int H = 128, W = 128;
    const int tid = threadIdx.x, x = tid & 31, yb = tid >> 5;
    const int b = blockIdx.z >> 2, ocb = (blockIdx.z & 3) * 16;
    const int tY = blockIdx.y * 32, tX = blockIdx.x * 32;
    const float s_in = 0.19245008972987526f;

    float acc[16][4];
#pragma unroll
    for (int oc = 0; oc < 16; ++oc)
#pragma unroll
        for (int k = 0; k < 4; ++k) acc[oc][k] = 0.f;

    for (int idx = tid; idx < 3 * 34 * 34; idx += 256) {
        int ic = idx / (34 * 34), p = idx % (34 * 34);
        int r = p / 34, c = p % 34;
        int gy = tY + r - 1, gx = tX + c - 1;
        float v = 0.f;
        if (gy >= 0 && gy < H && gx >= 0 && gx < W)
            v = in[((b * 3 + ic) * H + gy) * W + gx] * s_in;
        slds[ic][r][c] = v;
    }
    for (int idx = tid; idx < 3 * 9 * 16; idx += 256) {
        int oc = idx & 15, tap = (idx >> 4) % 9, ic = idx / 144;
        wlds[idx] = wgt[((ocb + oc) * 3 + ic) * 9 + tap];
    }
    __syncthreads();

#pragma unroll
    for (int ic = 0; ic < 3; ++ic)
#pragma unroll
        for (int dy = 0; dy < 3; ++dy)
#pragma unroll
            for (int dx = 0; dx < 3; ++dx) {
                float xv[4];
#pragma unroll
                for (int k = 0; k < 4; ++k)
                    xv[k] = slds[ic][yb + 8 * k + dy][x + dx];
                const float* wrow = &wlds[(ic * 9 + dy * 3 + dx) * 16];
#pragma unroll
                for (int oc = 0; oc < 16; ++oc) {
                    float wv = wrow[oc];
#pragma unroll
                    for (int k = 0; k < 4; ++k) acc[oc][k] = fmaf(wv, xv[k], acc[oc][k]);
                }
            }

#pragma unroll
    for (int oc = 0; oc < 16; ++oc) {
        int goc = ocb + oc;
        float bv = bias[goc];
#pragma unroll
        for (int k = 0; k < 4; ++k) {
            int gy = tY + yb + 8 * k, gx = tX + x;
            size_t pixG = ((size_t)b * H + gy) * W + gx;
            float v = acc[oc][k] + bv;
            outR[pixG * 64 + goc] = v;
            outT[pixG * 64 + goc] = __builtin_bit_cast(u16, (f16)v);
        }
    }
}

// --- unified MFMA conv template
// wave = 16 cols x ROWS rows x (MT/MG)*16 oc.  4 waves: cg/rg/mg split.
// INMODE: 1 = fp16 ch-last[64], 2 = fp16 planar16
// OUTMODE: 0 = fp16 ch-last + ReLU, 1 = fp32 trunk RMW + fp16 mirror,
//          2 = pixel-shuffle -> planar16 fp16, 3 = fp32 NCHW (oc<3)
template <int CG, int RG, int MG, int MT, int ROWS, int INMODE, int OUTMODE, int LB>
__global__ __launch_bounds__(256, LB) void mconv(
    const u16* __restrict__ inh, const f16* __restrict__ wp,
    const float* __restrict__ bias, float* __restrict__ rbuf,
    void* __restrict__ outv, u16* __restrict__ outT,
    int H, int W, int OCG, int wp_bstride, size_t in_pl, size_t out_pl)
{
    constexpr int TC = CG * 16, TR = RG * ROWS;
    constexpr int CST = TC + 2, RST = TR + 2;
    constexpr int PXT = RST * CST;
    constexpr int PXP = (PXT + 63) & ~63;
    constexpr int MT_W = MT / MG;
    constexpr int NW = CG * RG * MG;      // 4 waves
    constexpr int SB_H = 4 * PXP * 8;     // halfs
    constexpr int SA_H = 2 * 3 * MT * 512;

    __shared__ __align__(16) u16 smem[SB_H + SA_H];
    u16* sB = smem;
    u16* sA = smem + SB_H;

    const int tid = threadIdx.x;
    const int lane = tid & 63, wv = tid >> 6;
    const int lcol = lane & 15, lk8 = lane >> 4;
    const int cg = (CG > 1) ? (wv % CG) : 0;
    const int rg = (wv / CG) % RG;
    const int mg = wv / (CG * RG);
    const int b = blockIdx.z / OCG, ocg = blockIdx.z % OCG;
    const int y0 = blockIdx.y * TR, x0 = blockIdx.x * TC;
    const f16* wpb = wp + (size_t)b * wp_bstride + (size_t)ocg * 36864;

    auto stageA = [&](int kf, int dx, int buf) {
        for (int f = wv; f < 3 * MT; f += NW) {
            int dy = f / MT, mt = f - dy * MT;
            const f16* src = wpb + ((size_t)((dy * 3 + dx) * 2 + kf) * MT + mt) * 512 + lane * 8;
            gll16(src, sA + ((size_t)(buf * 3 * MT + f)) * 512 + lane * 8);
        }
    };
    auto stageB = [&](int kf) {
        for (int g0 = wv * 64; g0 < 4 * PXP; g0 += NW * 64) {
            int g = g0 + lane;
            int pl = g / PXP, px = g - pl * PXP;
            int t = px / CST, c = px - t * CST;
            int gy = y0 + t - 1, gx = x0 + c - 1;
            const void* src = g_zero;
            if (px < PXT && gy >= 0 && gy < H && gx >= 0 && gx < W) {
                size_t pix = ((size_t)b * H + gy) * W + gx;
                int ic = kf * 32 + pl * 8;
                if (INMODE == 1)
                    src = inh + pix * 64 + ic;
                else
                    src = inh + (size_t)(ic >> 4) * in_pl + pix * 16 + (ic & 15);
            }
            gll16(src, sB + (size_t)g * 8);
        }
    };

    f32x4 acc[ROWS][MT_W];
#pragma unroll
    for (int r = 0; r < ROWS; ++r)
#pragma unroll
        for (int m = 0; m < MT_W; ++m) acc[r][m] = (f32x4)0.f;

    stageB(0);
    stageA(0, 0, 0);
    __syncthreads();

    for (int s = 0; s < 6; ++s) {
        int kf = s / 3, dx = s - kf * 3;
        if (s == 3) {             // channel-half boundary: restage B
            stageB(1);
            __syncthreads();
        }
        if (s < 5) {
            int ns = s + 1;
            stageA(ns / 3, ns % 3, ns & 1);
        }
        // load A frags for this step
        f16x8 Af[3][MT_W];
        const int abase = (s & 1) * 3 * MT;
#pragma unroll
        for (int dy = 0; dy < 3; ++dy)
#pragma unroll
            for (int m = 0; m < MT_W; ++m)
                Af[dy][m] = *(const f16x8*)(sA + (size_t)(abase + dy * MT + mg * MT_W + m) * 512 + lane * 8);

        const u16* bbase = sB + (size_t)lk8 * PXP * 8;
        const int pcol = cg * 16 + dx + lcol;
#pragma unroll
        for (int iy = 0; iy < ROWS + 2; ++iy) {
            int px = (rg * ROWS + iy) * CST + pcol;
            f16x8 Bf = *(const f16x8*)(bbase + (size_t)px * 8);
#pragma unroll
            for (int dy = 0; dy < 3; ++dy) {
                constexpr int unused = 0; (void)unused;
                int r = iy - dy;
                if (r >= 0 && r < ROWS) {
#pragma unroll
                    for (int m = 0; m < MT_W; ++m)
                        acc[r][m] = __builtin_amdgcn_mfma_f32_16x16x32_f16(
                            Af[dy][m], Bf, acc[r][m], 0, 0, 0);
                }
            }
        }
        __syncthreads();
    }

    // ---- epilogue. C/D: col(px)=lane&15, row(oc)=lk8*4+reg
    if (OUTMODE == 0 || OUTMODE == 1) {
        u16* outh = (u16*)outv;
#pragma unroll
        for (int r = 0; r < ROWS; ++r) {
            int gy = y0 + rg * ROWS + r, gx = x0 + cg * 16 + lcol;
            size_t pixG = ((size_t)b * H + gy) * W + gx;
#pragma unroll
            for (int m = 0; m < MT_W; ++m) {
                int oc0 = (mg * MT_W + m) * 16 + lk8 * 4;
                f32x4 v = acc[r][m] + *(const f32x4*)(bias + oc0);
                if (OUTMODE == 0) {
                    f16x4 o;
#pragma unroll
                    for (int j = 0; j < 4; ++j) o[j] = (f16)fmaxf(v[j], 0.f);
                    *(f16x4*)(outh + pixG * 64 + oc0) = o;
                } else {
                    float* rp = rbuf + pixG * 64 + oc0;
                    f32x4 rv = *(const f32x4*)rp;
                    v += rv;
                    *(f32x4*)rp = v;
                    f16x4 o;
#pragma unroll
                    for (int j = 0; j < 4; ++j) o[j] = (f16)v[j];
                    *(f16x4*)(outT + pixG * 64 + oc0) = o;
                }
            }
        }
    } else if (OUTMODE == 2) {
        // pixel shuffle via LDS transpose: sT[16 cc][NP pairs] u32
        constexpr int NP = 2 * TR * TC;   // x-pairs * out-rows
        __syncthreads();
        u32* sT = (u32*)smem;
#pragma unroll
        for (int r = 0; r < ROWS; ++r) {
#pragma unroll
            for (int m = 0; m < MT_W; ++m) {
                int oc0 = m * 16 + lk8 * 4;
                int cc = m * 4 + lk8;
                f32x4 v = acc[r][m] + *(const f32x4*)(bias + ocg * 64 + oc0);
                int oy = 2 * (rg * ROWS + r);
#pragma unroll
                for (int jp = 0; jp < 2; ++jp) {
                    f16 e0 = (f16)v[jp * 2], e1 = (f16)v[jp * 2 + 1];
                    u32 w = (u32)__builtin_bit_cast(u16, e0) |
                            ((u32)__builtin_bit_cast(u16, e1) << 16);
                    sT[cc * NP + (oy + jp) * TC + cg * 16 + lcol] = w;
                }
            }
        }
        __syncthreads();
        u16* outh = (u16*)outv + (size_t)ocg * out_pl;
        const int H2 = 2 * H, W2 = 2 * W;
#pragma unroll
        for (int it = 0; it < NP / 256; ++it) {
            int p = tid + it * 256;
            int oy = p / TC, xp = p - oy * TC;
            u32 tv[16];
#pragma unroll
            for (int c = 0; c < 16; ++c) tv[c] = sT[c * NP + p];
            u32 q0[8], q1[8];
#pragma unroll
            for (int c2 = 0; c2 < 8; ++c2) {
                q0[c2] = (tv[2 * c2] & 0xffffu) | (tv[2 * c2 + 1] << 16);
                q1[c2] = (tv[2 * c2] >> 16) | (tv[2 * c2 + 1] & 0xffff0000u);
            }
            int gy2 = 2 * y0 + oy, gx2 = 2 * x0 + 2 * xp;
            u16* dst = outh + (((size_t)b * H2 + gy2) * W2 + gx2) * 16;
            *(u32x4*)(dst)      = *(u32x4*)(q0);
            *(u32x4*)(dst + 8)  = *(u32x4*)(q0 + 4);
            *(u32x4*)(dst + 16) = *(u32x4*)(q1);
            *(u32x4*)(dst + 24) = *(u32x4*)(q1 + 4);
        }
    } else {
        // OUTMODE 3: fp32 NCHW, oc<3
        float* outp = (float*)outv;
        if (lk8 == 0) {
#pragma unroll
            for (int r = 0; r < ROWS; ++r) {
                int gy = y0 + rg * ROWS + r, gx = x0 + cg * 16 + lcol;
#pragma unroll
                for (int j = 0; j < 3; ++j) {
                    float v = acc[r][0][j] + bias[j];
                    outp[(((size_t)b * 3 + j) * H + gy) * W + gx] = v;
                }
            }
        }
    }
}

extern "C" void kernel_launch(void* const* d_in, const int* in_sizes, int n_in,
                              void* d_out, int out_size, void* d_ws, size_t ws_size,
                              hipStream_t stream) {
    const float* x     = (const float*)d_in[0];
    const float* cf    = (const float*)d_in[1];
    const float* in_w  = (const float*)d_in[2];
    const float* in_b  = (const float*)d_in[3];
    const float* blk_w = (const float*)d_in[4];
    const float* blk_b = (const float*)d_in[5];
    const float* mod_w = (const float*)d_in[6];
    const float* mod_b = (const float*)d_in[7];
    const float* up_w  = (const float*)d_in[8];
    const float* up_b  = (const float*)d_in[9];
    const float* out_w = (const float*)d_in[10];
    const float* out_b = (const float*)d_in[11];
    float* outp = (float*)d_out;

    u16 *bufT, *bufB, *bufC, *bufE;
    float *bufR, *modp;
    f16 *wblk, *wup, *wout;
    hipGetSymbolAddress((void**)&bufT, HIP_SYMBOL(g_bufT));
    hipGetSymbolAddress((void**)&bufR, HIP_SYMBOL(g_bufR));
    hipGetSymbolAddress((void**)&bufB, HIP_SYMBOL(g_bufB));
    hipGetSymbolAddress((void**)&bufC, HIP_SYMBOL(g_bufC));
    hipGetSymbolAddress((void**)&bufE, HIP_SYMBOL(g_bufE));
    hipGetSymbolAddress((void**)&modp, HIP_SYMBOL(g_mod));
    hipGetSymbolAddress((void**)&wblk, HIP_SYMBOL(g_wblk));
    hipGetSymbolAddress((void**)&wup,  HIP_SYMBOL(g_wup));
    hipGetSymbolAddress((void**)&wout, HIP_SYMBOL(g_wout));

    mod_kernel<<<dim3(20, 4), 64, 0, stream>>>(cf, mod_w, mod_b, modp);
    prep_blk_kernel<<<dim3(20, 4), 256, 0, stream>>>(blk_w, modp, wblk);
    prep_up_kernel<<<dim3(2, 4), 256, 0, stream>>>(up_w, wup);
    prep_out_kernel<<<1, 256, 0, stream>>>(out_w, wout);

    in_conv_kernel<<<dim3(4, 4, 16), 256, 0, stream>>>(x, in_w, in_b, bufR, bufT);

    const size_t PLC = (size_t)4 * 256 * 256 * 16;
    const size_t PLE = (size_t)4 * 512 * 512 * 16;

    for (int i = 0; i < 10; ++i) {
        // conv1: bufT -> bufB (fp16, ReLU)
        mconv<1, 2, 2, 4, 4, 1, 0, 2><<<dim3(8, 16, 4), 256, 0, stream>>>(
            bufT, wblk + (size_t)(2 * i) * 4 * 36864, blk_b + (2 * i) * 64,
            nullptr, bufB, nullptr, 128, 128, 1, 36864, 0, 0);
        // conv2: bufB -> trunk RMW (bufR fp32) + bufT mirror
        mconv<1, 2, 2, 4, 4, 1, 1, 2><<<dim3(8, 16, 4), 256, 0, stream>>>(
            bufB, wblk + (size_t)(2 * i + 1) * 4 * 36864, blk_b + (2 * i + 1) * 64,
            bufR, nullptr, bufT, 128, 128, 1, 36864, 0, 0);
    }

    // up0: bufT @128^2 -> shuffle -> bufC (planar16, 256^2)
    mconv<2, 2, 1, 4, 8, 1, 2, 2><<<dim3(4, 8, 16), 256, 0, stream>>>(
        bufT, wup, up_b, nullptr, bufC, nullptr, 128, 128, 4, 0, 0, PLC);
    // up1: bufC @256^2 -> shuffle -> bufE (planar16, 512^2)
    mconv<2, 2, 1, 4, 8, 2, 2, 2><<<dim3(8, 16, 16), 256, 0, stream>>>(
        bufC, wup + (size_t)4 * 36864, up_b + 256, nullptr, bufE, nullptr,
        256, 256, 4, 0, PLC, PLE);
    // out: bufE @512^2 -> fp32 NCHW (3 ch)
    mconv<2, 2, 1, 1, 8, 2, 3, 3><<<dim3(16, 32, 4), 256, 0, stream>>>(
        bufE, wout, out_b, nullptr, outp, nullptr, 512, 512, 1, 0, PLE, 0);
}